// Round 1
// baseline (354.109 us; speedup 1.0000x reference)
//
#include <hip/hip_runtime.h>
#include <math.h>

#define LN_EPS 1e-5f
// B=2 L=512 D=512 H=8 DH=64 C=64 F=2048

// ---------------------------------------------------------------------------
// K0: qw[b,i,h,c] = sum_d q[h*64+d]*rel_w[(h*64+d)*64+c] ; qb = q . rel_b (per head)
// ---------------------------------------------------------------------------
__global__ __launch_bounds__(256) void qw_kernel(
    const float* __restrict__ src, const float* __restrict__ rel_w,
    const float* __restrict__ rel_b, float* __restrict__ qw, float* __restrict__ qb)
{
  const int bi = blockIdx.x;     // b*512 + i
  const int tid = threadIdx.x;
  __shared__ float q_sh[512];
  q_sh[tid]       = src[bi*512 + tid];
  q_sh[tid + 256] = src[bi*512 + tid + 256];
  __syncthreads();
  for (int idx = tid; idx < 512; idx += 256) {
    const int h = idx >> 6, c = idx & 63;
    float s = 0.f;
    #pragma unroll 8
    for (int d = 0; d < 64; ++d)
      s = fmaf(q_sh[h*64+d], rel_w[(h*64+d)*64 + c], s);
    qw[bi*512 + idx] = s;
  }
  if (tid < 8) {
    float s = 0.f;
    for (int d = 0; d < 64; ++d) s = fmaf(q_sh[tid*64+d], rel_b[tid*64+d], s);
    qb[bi*8 + tid] = s;
  }
}

// ---------------------------------------------------------------------------
// K1: fused attention per (b,i): scores (rel+base) -> softmax -> PV -> +res -> LN1
// ---------------------------------------------------------------------------
__global__ __launch_bounds__(256) void attn_kernel(
    const float* __restrict__ src, const float* __restrict__ rel,
    const float* __restrict__ qw, const float* __restrict__ qb,
    const float* __restrict__ g1, const float* __restrict__ be1,
    float* __restrict__ xout)
{
  const int bi  = blockIdx.x;    // b*512 + i
  const int b   = bi >> 9;
  const int tid = threadIdx.x;

  __shared__ float qs_sh[512];     // q * 0.125 (for base scores)
  __shared__ float qw_sh[512];     // qw[h][c]
  __shared__ float s_sh[8][512];   // scores then probabilities
  __shared__ float red1[4], red2[4];

  for (int d = tid; d < 512; d += 256) {
    qs_sh[d] = src[bi*512 + d] * 0.125f;
    qw_sh[d] = qw[bi*512 + d];
  }
  __syncthreads();

  // ---- Phase A: scores s[h][j] for j = tid and tid+256 ----
  {
    const int j = tid, j2 = tid + 256;
    float acc[8], acc2[8];
    #pragma unroll
    for (int h = 0; h < 8; ++h) { const float qbv = qb[bi*8 + h]; acc[h] = qbv; acc2[h] = qbv; }

    // rel part: sum_c RF[b,i,j,c] * qw[h][c]
    const float4* rf  = (const float4*)(rel + ((size_t)bi*512 + j )*64);
    const float4* rf2 = (const float4*)(rel + ((size_t)bi*512 + j2)*64);
    const float4* qw4 = (const float4*)qw_sh;
    #pragma unroll
    for (int cc = 0; cc < 16; ++cc) {
      const float4 v = rf[cc], v2 = rf2[cc];
      #pragma unroll
      for (int h = 0; h < 8; ++h) {
        const float4 w = qw4[h*16 + cc];
        acc [h] += v .x*w.x + v .y*w.y + v .z*w.z + v .w*w.w;
        acc2[h] += v2.x*w.x + v2.y*w.y + v2.z*w.z + v2.w*w.w;
      }
    }

    // base part: sum_{d in head h} (q*scale)[d] * k_j[d]
    const float4* k4  = (const float4*)(src + ((size_t)(b*512) + j )*512);
    const float4* k42 = (const float4*)(src + ((size_t)(b*512) + j2)*512);
    const float4* qs4 = (const float4*)qs_sh;
    #pragma unroll
    for (int h = 0; h < 8; ++h) {
      float a = 0.f, a2 = 0.f;
      #pragma unroll
      for (int t = 0; t < 16; ++t) {
        const int cc = h*16 + t;
        const float4 q = qs4[cc];
        const float4 k = k4[cc], k2 = k42[cc];
        a  += k .x*q.x + k .y*q.y + k .z*q.z + k .w*q.w;
        a2 += k2.x*q.x + k2.y*q.y + k2.z*q.z + k2.w*q.w;
      }
      acc[h] += a; acc2[h] += a2;
    }

    #pragma unroll
    for (int h = 0; h < 8; ++h) { s_sh[h][j] = acc[h]; s_sh[h][j2] = acc2[h]; }
  }
  __syncthreads();

  // ---- Phase B: softmax over j for each head (each wave: 2 heads) ----
  {
    const int w = tid >> 6, lane = tid & 63;
    #pragma unroll
    for (int hh = 0; hh < 2; ++hh) {
      const int h = w + hh*4;
      float m = -1e30f;
      for (int j = lane; j < 512; j += 64) m = fmaxf(m, s_sh[h][j]);
      #pragma unroll
      for (int o = 32; o > 0; o >>= 1) m = fmaxf(m, __shfl_xor(m, o, 64));
      float sum = 0.f;
      for (int j = lane; j < 512; j += 64) {
        const float e = __expf(s_sh[h][j] - m);
        s_sh[h][j] = e; sum += e;
      }
      #pragma unroll
      for (int o = 32; o > 0; o >>= 1) sum += __shfl_xor(sum, o, 64);
      const float r = 1.f / sum;
      for (int j = lane; j < 512; j += 64) s_sh[h][j] *= r;
    }
  }
  __syncthreads();

  // ---- Phase C: PV + residual + LN1 ----
  {
    const int d0 = tid * 2;
    const int h  = d0 >> 6;
    float acc0 = 0.f, acc1 = 0.f;
    const float2* vb2 = (const float2*)(src + (size_t)b*512*512);
    for (int j = 0; j < 512; ++j) {
      const float p = s_sh[h][j];
      const float2 v = vb2[j*256 + tid];
      acc0 += p * v.x; acc1 += p * v.y;
    }
    const float y0 = src[bi*512 + d0]     + acc0;
    const float y1 = src[bi*512 + d0 + 1] + acc1;

    float s1 = y0 + y1, s2 = y0*y0 + y1*y1;
    #pragma unroll
    for (int o = 32; o > 0; o >>= 1) { s1 += __shfl_xor(s1, o, 64); s2 += __shfl_xor(s2, o, 64); }
    const int w = tid >> 6;
    if ((tid & 63) == 0) { red1[w] = s1; red2[w] = s2; }
    __syncthreads();
    const float t1 = red1[0] + red1[1] + red1[2] + red1[3];
    const float t2 = red2[0] + red2[1] + red2[2] + red2[3];
    const float mu  = t1 * (1.f/512.f);
    const float var = t2 * (1.f/512.f) - mu*mu;
    const float rs  = rsqrtf(var + LN_EPS);
    xout[bi*512 + d0]     = (y0 - mu)*rs*g1[d0]     + be1[d0];
    xout[bi*512 + d0 + 1] = (y1 - mu)*rs*g1[d0 + 1] + be1[d0 + 1];
  }
}

// ---------------------------------------------------------------------------
// K2: ff = leaky_relu(x @ w1^T + b1)   [1024,512]x[2048,512]^T -> [1024,2048]
// ---------------------------------------------------------------------------
__global__ __launch_bounds__(256) void ffn1_kernel(
    const float* __restrict__ x, const float* __restrict__ w1,
    const float* __restrict__ b1, float* __restrict__ ff)
{
  __shared__ float As[16][68];
  __shared__ float Bs[16][68];
  const int tid = threadIdx.x;
  const int m0 = blockIdx.x * 64;
  const int n0 = blockIdx.y * 64;
  const int tm = (tid & 15) * 4;
  const int tn = (tid >> 4) * 4;
  const int lr = tid >> 4, lc = tid & 15;
  float acc[4][4] = {};
  for (int k0 = 0; k0 < 512; k0 += 16) {
    #pragma unroll
    for (int r = lr; r < 64; r += 16) {
      As[lc][r] = x [(m0 + r)*512 + k0 + lc];
      Bs[lc][r] = w1[(n0 + r)*512 + k0 + lc];
    }
    __syncthreads();
    #pragma unroll
    for (int k = 0; k < 16; ++k) {
      const float4 a  = *(const float4*)&As[k][tm];
      const float4 bv = *(const float4*)&Bs[k][tn];
      acc[0][0] += a.x*bv.x; acc[0][1] += a.x*bv.y; acc[0][2] += a.x*bv.z; acc[0][3] += a.x*bv.w;
      acc[1][0] += a.y*bv.x; acc[1][1] += a.y*bv.y; acc[1][2] += a.y*bv.z; acc[1][3] += a.y*bv.w;
      acc[2][0] += a.z*bv.x; acc[2][1] += a.z*bv.y; acc[2][2] += a.z*bv.z; acc[2][3] += a.z*bv.w;
      acc[3][0] += a.w*bv.x; acc[3][1] += a.w*bv.y; acc[3][2] += a.w*bv.z; acc[3][3] += a.w*bv.w;
    }
    __syncthreads();
  }
  #pragma unroll
  for (int i = 0; i < 4; ++i) {
    float4 v;
    float vv[4];
    #pragma unroll
    for (int jj = 0; jj < 4; ++jj) {
      float t = acc[i][jj] + b1[n0 + tn + jj];
      vv[jj] = t > 0.f ? t : 0.01f*t;
    }
    v.x = vv[0]; v.y = vv[1]; v.z = vv[2]; v.w = vv[3];
    *(float4*)&ff[(size_t)(m0 + tm + i)*2048 + n0 + tn] = v;
  }
}

// ---------------------------------------------------------------------------
// K3: split-K GEMM2 partials: p[z][m,d] = sum_{f in half z} ff[m,f]*w2[d,f]
// ---------------------------------------------------------------------------
__global__ __launch_bounds__(256) void ffn2_kernel(
    const float* __restrict__ ff, const float* __restrict__ w2,
    float* __restrict__ p0, float* __restrict__ p1)
{
  __shared__ float As[16][68];
  __shared__ float Bs[16][68];
  const int tid = threadIdx.x;
  const int m0 = blockIdx.x * 64;
  const int n0 = blockIdx.y * 64;
  const int kbase = blockIdx.z * 1024;
  float* outp = blockIdx.z ? p1 : p0;
  const int tm = (tid & 15) * 4;
  const int tn = (tid >> 4) * 4;
  const int lr = tid >> 4, lc = tid & 15;
  float acc[4][4] = {};
  for (int k0 = 0; k0 < 1024; k0 += 16) {
    #pragma unroll
    for (int r = lr; r < 64; r += 16) {
      As[lc][r] = ff[(size_t)(m0 + r)*2048 + kbase + k0 + lc];
      Bs[lc][r] = w2[(size_t)(n0 + r)*2048 + kbase + k0 + lc];
    }
    __syncthreads();
    #pragma unroll
    for (int k = 0; k < 16; ++k) {
      const float4 a  = *(const float4*)&As[k][tm];
      const float4 bv = *(const float4*)&Bs[k][tn];
      acc[0][0] += a.x*bv.x; acc[0][1] += a.x*bv.y; acc[0][2] += a.x*bv.z; acc[0][3] += a.x*bv.w;
      acc[1][0] += a.y*bv.x; acc[1][1] += a.y*bv.y; acc[1][2] += a.y*bv.z; acc[1][3] += a.y*bv.w;
      acc[2][0] += a.z*bv.x; acc[2][1] += a.z*bv.y; acc[2][2] += a.z*bv.z; acc[2][3] += a.z*bv.w;
      acc[3][0] += a.w*bv.x; acc[3][1] += a.w*bv.y; acc[3][2] += a.w*bv.z; acc[3][3] += a.w*bv.w;
    }
    __syncthreads();
  }
  #pragma unroll
  for (int i = 0; i < 4; ++i) {
    float4 v; v.x = acc[i][0]; v.y = acc[i][1]; v.z = acc[i][2]; v.w = acc[i][3];
    *(float4*)&outp[(m0 + tm + i)*512 + n0 + tn] = v;
  }
}

// ---------------------------------------------------------------------------
// K4: out = LN(x + p0 + p1 + b2) * g2 + be2
// ---------------------------------------------------------------------------
__global__ __launch_bounds__(256) void ln2_kernel(
    const float* __restrict__ p0, const float* __restrict__ p1,
    const float* __restrict__ x, const float* __restrict__ b2,
    const float* __restrict__ g2, const float* __restrict__ be2,
    float* __restrict__ out)
{
  const int bi = blockIdx.x, tid = threadIdx.x;
  const int d0 = tid * 2;
  const float2 a0 = *(const float2*)&p0[bi*512 + d0];
  const float2 a1 = *(const float2*)&p1[bi*512 + d0];
  const float2 xr = *(const float2*)&x [bi*512 + d0];
  const float2 bb = *(const float2*)&b2[d0];
  const float y0 = a0.x + a1.x + bb.x + xr.x;
  const float y1 = a0.y + a1.y + bb.y + xr.y;
  float s1 = y0 + y1, s2 = y0*y0 + y1*y1;
  #pragma unroll
  for (int o = 32; o > 0; o >>= 1) { s1 += __shfl_xor(s1, o, 64); s2 += __shfl_xor(s2, o, 64); }
  __shared__ float r1[4], r2[4];
  const int w = tid >> 6;
  if ((tid & 63) == 0) { r1[w] = s1; r2[w] = s2; }
  __syncthreads();
  const float t1 = r1[0] + r1[1] + r1[2] + r1[3];
  const float t2 = r2[0] + r2[1] + r2[2] + r2[3];
  const float mu  = t1 * (1.f/512.f);
  const float var = t2 * (1.f/512.f) - mu*mu;
  const float rs  = rsqrtf(var + LN_EPS);
  const float2 g  = *(const float2*)&g2 [d0];
  const float2 be = *(const float2*)&be2[d0];
  out[bi*512 + d0]     = (y0 - mu)*rs*g.x + be.x;
  out[bi*512 + d0 + 1] = (y1 - mu)*rs*g.y + be.y;
}

// ---------------------------------------------------------------------------
extern "C" void kernel_launch(void* const* d_in, const int* in_sizes, int n_in,
                              void* d_out, int out_size, void* d_ws, size_t ws_size,
                              hipStream_t stream) {
  const float* src  = (const float*)d_in[0];
  const float* relf = (const float*)d_in[1];
  const float* rel_w = (const float*)d_in[2];
  const float* rel_b = (const float*)d_in[3];
  const float* w1 = (const float*)d_in[4];
  const float* b1 = (const float*)d_in[5];
  const float* w2 = (const float*)d_in[6];
  const float* b2 = (const float*)d_in[7];
  const float* g1  = (const float*)d_in[8];
  const float* be1 = (const float*)d_in[9];
  const float* g2  = (const float*)d_in[10];
  const float* be2 = (const float*)d_in[11];
  float* out = (float*)d_out;

  float* ws = (float*)d_ws;
  float* qw = ws;                 // 524288
  float* qb = qw + 524288;        // 8192
  float* x  = qb + 8192;          // 524288
  float* ff = x  + 524288;        // 2097152
  float* p0 = ff + 2097152;       // 524288
  float* p1 = p0 + 524288;        // 524288  (total ~16.8 MB)

  qw_kernel  <<<1024, 256, 0, stream>>>(src, rel_w, rel_b, qw, qb);
  attn_kernel<<<1024, 256, 0, stream>>>(src, relf, qw, qb, g1, be1, x);
  ffn1_kernel<<<dim3(16, 32), 256, 0, stream>>>(x, w1, b1, ff);
  ffn2_kernel<<<dim3(16, 8, 2), 256, 0, stream>>>(ff, w2, p0, p1);
  ln2_kernel <<<1024, 256, 0, stream>>>(p0, p1, x, b2, g2, be2, out);
}

// Round 2
// 232.508 us; speedup vs baseline: 1.5230x; 1.5230x over previous
//
#include <hip/hip_runtime.h>
#include <math.h>

#define LN_EPS 1e-5f
// B=2 L=512 D=512 H=8 DH=64 C=64 F=2048
// S layout: S[b,h,i,j] = S[((b*8+h)*512 + i)*512 + j]

// ---------------------------------------------------------------------------
// K0: qw[b,i,h,c] = sum_d q[h*64+d]*rel_w[(h*64+d)*64+c] ; qb = q . rel_b (per head)
// ---------------------------------------------------------------------------
__global__ __launch_bounds__(256) void qw_kernel(
    const float* __restrict__ src, const float* __restrict__ rel_w,
    const float* __restrict__ rel_b, float* __restrict__ qw, float* __restrict__ qb)
{
  const int bi = blockIdx.x;     // b*512 + i
  const int tid = threadIdx.x;
  __shared__ float q_sh[512];
  q_sh[tid]       = src[bi*512 + tid];
  q_sh[tid + 256] = src[bi*512 + tid + 256];
  __syncthreads();
  for (int idx = tid; idx < 512; idx += 256) {
    const int h = idx >> 6, c = idx & 63;
    float s = 0.f;
    #pragma unroll 8
    for (int d = 0; d < 64; ++d)
      s = fmaf(q_sh[h*64+d], rel_w[(h*64+d)*64 + c], s);
    qw[bi*512 + idx] = s;
  }
  if (tid < 8) {
    float s = 0.f;
    for (int d = 0; d < 64; ++d) s = fmaf(q_sh[tid*64+d], rel_b[tid*64+d], s);
    qb[bi*8 + tid] = s;
  }
}

// ---------------------------------------------------------------------------
// K1: S[b,h,i,j] = scale * q_i . q_j (head slice) + qb[b,i,h]
// grid (bh=16, it=8, jt=8), 64x64 tile, K=64
// ---------------------------------------------------------------------------
__global__ __launch_bounds__(256) void base_kernel(
    const float* __restrict__ src, const float* __restrict__ qb,
    float* __restrict__ S)
{
  const int bh = blockIdx.x, it = blockIdx.y, jt = blockIdx.z;
  const int b = bh >> 3, h = bh & 7;
  const int i0 = it*64, j0 = jt*64;
  const int tid = threadIdx.x;
  __shared__ float As[64][68];
  __shared__ float Bs[64][68];
  const float* sb = src + (size_t)b*512*512 + h*64;
  for (int idx = tid; idx < 4096; idx += 256) {
    const int k = idx & 63, m = idx >> 6;
    As[k][m] = sb[(size_t)(i0+m)*512 + k] * 0.125f;
    Bs[k][m] = sb[(size_t)(j0+m)*512 + k];
  }
  __syncthreads();
  const int tm = (tid & 15)*4, tn = (tid >> 4)*4;
  float acc[4][4] = {};
  #pragma unroll
  for (int k = 0; k < 64; ++k) {
    const float4 a  = *(const float4*)&As[k][tm];
    const float4 bv = *(const float4*)&Bs[k][tn];
    acc[0][0] += a.x*bv.x; acc[0][1] += a.x*bv.y; acc[0][2] += a.x*bv.z; acc[0][3] += a.x*bv.w;
    acc[1][0] += a.y*bv.x; acc[1][1] += a.y*bv.y; acc[1][2] += a.y*bv.z; acc[1][3] += a.y*bv.w;
    acc[2][0] += a.z*bv.x; acc[2][1] += a.z*bv.y; acc[2][2] += a.z*bv.z; acc[2][3] += a.z*bv.w;
    acc[3][0] += a.w*bv.x; acc[3][1] += a.w*bv.y; acc[3][2] += a.w*bv.z; acc[3][3] += a.w*bv.w;
  }
  float* Sp = S + ((size_t)bh*512 + i0)*512 + j0;
  #pragma unroll
  for (int ii = 0; ii < 4; ++ii) {
    const float qbv = qb[(size_t)(b*512 + i0 + tm + ii)*8 + h];
    float4 v;
    v.x = acc[ii][0] + qbv; v.y = acc[ii][1] + qbv;
    v.z = acc[ii][2] + qbv; v.w = acc[ii][3] + qbv;
    *(float4*)&Sp[(size_t)(tm+ii)*512 + tn] = v;
  }
}

// ---------------------------------------------------------------------------
// K2: S[b,h,i,j] += sum_c RF[b,i,j,c] * qw[b,i,h,c]
// grid (bi=1024, jt=8): 64-j tile staged in LDS (coalesced), 8 heads
// ---------------------------------------------------------------------------
__global__ __launch_bounds__(256) void rel_kernel(
    const float* __restrict__ rel, const float* __restrict__ qw,
    float* __restrict__ S)
{
  const int bi = blockIdx.x, jt = blockIdx.y;
  const int b = bi >> 9, i = bi & 511;
  const int j0 = jt * 64;
  const int tid = threadIdx.x;
  __shared__ float RF[64*65];
  __shared__ float QW[512];
  QW[tid]       = qw[(size_t)bi*512 + tid];
  QW[tid + 256] = qw[(size_t)bi*512 + tid + 256];
  const float4* rg = (const float4*)(rel + ((size_t)bi*512 + j0)*64);
  #pragma unroll
  for (int p = 0; p < 4; ++p) {
    const int f = p*256 + tid;         // float4 index within 64x64 tile
    const float4 v = rg[f];
    const int j = f >> 4, c = (f & 15)*4;
    float* dst = &RF[j*65 + c];
    dst[0]=v.x; dst[1]=v.y; dst[2]=v.z; dst[3]=v.w;
  }
  __syncthreads();
  const int j = tid & 63, hg = tid >> 6;   // heads hg and hg+4
  const float* rfj = &RF[j*65];
  const float* q0 = &QW[hg*64];
  const float* q1 = &QW[(hg+4)*64];
  float a0 = 0.f, a1 = 0.f;
  #pragma unroll
  for (int c = 0; c < 64; ++c) {
    const float r = rfj[c];
    a0 = fmaf(r, q0[c], a0);
    a1 = fmaf(r, q1[c], a1);
  }
  const size_t base = ((size_t)(b*8+hg)*512 + i)*512 + j0 + j;
  S[base] += a0;
  S[base + (size_t)4*512*512] += a1;
}

// ---------------------------------------------------------------------------
// K3: softmax rows of S + PV -> attn_out[b,i,h*64+d]
// grid (bh=16, it=32): 16 i-rows per block
// ---------------------------------------------------------------------------
__global__ __launch_bounds__(256) void softmax_pv_kernel(
    const float* __restrict__ S, const float* __restrict__ src,
    float* __restrict__ attn_out)
{
  const int bh = blockIdx.x, it = blockIdx.y;
  const int b = bh >> 3, h = bh & 7;
  const int i0 = it * 16;
  const int tid = threadIdx.x;
  const int lane = tid & 63, w = tid >> 6;
  __shared__ float Pt[512*20];   // transposed P: [j][i_local], row pad 20

  // softmax: wave w handles rows w*4 .. w*4+3
  #pragma unroll
  for (int k = 0; k < 4; ++k) {
    const int il = w*4 + k;
    const float* Srow = S + ((size_t)bh*512 + i0 + il)*512;
    float v[8];
    float m = -1e30f;
    #pragma unroll
    for (int r = 0; r < 8; ++r) { v[r] = Srow[lane + 64*r]; m = fmaxf(m, v[r]); }
    #pragma unroll
    for (int o = 32; o > 0; o >>= 1) m = fmaxf(m, __shfl_xor(m, o, 64));
    float s = 0.f;
    #pragma unroll
    for (int r = 0; r < 8; ++r) { v[r] = __expf(v[r] - m); s += v[r]; }
    #pragma unroll
    for (int o = 32; o > 0; o >>= 1) s += __shfl_xor(s, o, 64);
    const float inv = 1.f / s;
    #pragma unroll
    for (int r = 0; r < 8; ++r) Pt[(lane + 64*r)*20 + il] = v[r] * inv;
  }
  __syncthreads();

  // PV: thread = (d=lane, ig=w) accumulates 4 i-rows
  const int d = lane, ig = w;
  const float* V = src + (size_t)b*512*512 + h*64 + d;
  float acc0=0.f, acc1=0.f, acc2=0.f, acc3=0.f;
  #pragma unroll 8
  for (int j = 0; j < 512; ++j) {
    const float vv = V[(size_t)j*512];
    const float4 p = *(const float4*)&Pt[j*20 + ig*4];
    acc0 = fmaf(p.x, vv, acc0); acc1 = fmaf(p.y, vv, acc1);
    acc2 = fmaf(p.z, vv, acc2); acc3 = fmaf(p.w, vv, acc3);
  }
  float* out = attn_out + ((size_t)(b*512) + i0)*512 + h*64 + d;
  out[(size_t)(ig*4+0)*512] = acc0;
  out[(size_t)(ig*4+1)*512] = acc1;
  out[(size_t)(ig*4+2)*512] = acc2;
  out[(size_t)(ig*4+3)*512] = acc3;
}

// ---------------------------------------------------------------------------
// K4: x = LN(src + attn_out) * g1 + be1
// ---------------------------------------------------------------------------
__global__ __launch_bounds__(256) void ln1_kernel(
    const float* __restrict__ a, const float* __restrict__ bb,
    const float* __restrict__ g, const float* __restrict__ be,
    float* __restrict__ out)
{
  const int bi = blockIdx.x, tid = threadIdx.x;
  const int d0 = tid * 2;
  const float2 xa = *(const float2*)&a [bi*512 + d0];
  const float2 xb = *(const float2*)&bb[bi*512 + d0];
  const float y0 = xa.x + xb.x;
  const float y1 = xa.y + xb.y;
  float s1 = y0 + y1, s2 = y0*y0 + y1*y1;
  #pragma unroll
  for (int o = 32; o > 0; o >>= 1) { s1 += __shfl_xor(s1, o, 64); s2 += __shfl_xor(s2, o, 64); }
  __shared__ float r1[4], r2[4];
  const int w = tid >> 6;
  if ((tid & 63) == 0) { r1[w] = s1; r2[w] = s2; }
  __syncthreads();
  const float t1 = r1[0] + r1[1] + r1[2] + r1[3];
  const float t2 = r2[0] + r2[1] + r2[2] + r2[3];
  const float mu  = t1 * (1.f/512.f);
  const float var = t2 * (1.f/512.f) - mu*mu;
  const float rs  = rsqrtf(var + LN_EPS);
  const float2 gg = *(const float2*)&g [d0];
  const float2 bv = *(const float2*)&be[d0];
  out[bi*512 + d0]     = (y0 - mu)*rs*gg.x + bv.x;
  out[bi*512 + d0 + 1] = (y1 - mu)*rs*gg.y + bv.y;
}

// ---------------------------------------------------------------------------
// K5: ff = leaky_relu(x @ w1^T + b1)
// ---------------------------------------------------------------------------
__global__ __launch_bounds__(256) void ffn1_kernel(
    const float* __restrict__ x, const float* __restrict__ w1,
    const float* __restrict__ b1, float* __restrict__ ff)
{
  __shared__ float As[16][68];
  __shared__ float Bs[16][68];
  const int tid = threadIdx.x;
  const int m0 = blockIdx.x * 64;
  const int n0 = blockIdx.y * 64;
  const int tm = (tid & 15) * 4;
  const int tn = (tid >> 4) * 4;
  const int lr = tid >> 4, lc = tid & 15;
  float acc[4][4] = {};
  for (int k0 = 0; k0 < 512; k0 += 16) {
    #pragma unroll
    for (int r = lr; r < 64; r += 16) {
      As[lc][r] = x [(m0 + r)*512 + k0 + lc];
      Bs[lc][r] = w1[(n0 + r)*512 + k0 + lc];
    }
    __syncthreads();
    #pragma unroll
    for (int k = 0; k < 16; ++k) {
      const float4 a  = *(const float4*)&As[k][tm];
      const float4 bv = *(const float4*)&Bs[k][tn];
      acc[0][0] += a.x*bv.x; acc[0][1] += a.x*bv.y; acc[0][2] += a.x*bv.z; acc[0][3] += a.x*bv.w;
      acc[1][0] += a.y*bv.x; acc[1][1] += a.y*bv.y; acc[1][2] += a.y*bv.z; acc[1][3] += a.y*bv.w;
      acc[2][0] += a.z*bv.x; acc[2][1] += a.z*bv.y; acc[2][2] += a.z*bv.z; acc[2][3] += a.z*bv.w;
      acc[3][0] += a.w*bv.x; acc[3][1] += a.w*bv.y; acc[3][2] += a.w*bv.z; acc[3][3] += a.w*bv.w;
    }
    __syncthreads();
  }
  #pragma unroll
  for (int i = 0; i < 4; ++i) {
    float4 v;
    #pragma unroll
    for (int jj = 0; jj < 4; ++jj) {
      float t = acc[i][jj] + b1[n0 + tn + jj];
      ((float*)&v)[jj] = t > 0.f ? t : 0.01f*t;
    }
    *(float4*)&ff[(size_t)(m0 + tm + i)*2048 + n0 + tn] = v;
  }
}

// ---------------------------------------------------------------------------
// K6: split-K GEMM2 partials
// ---------------------------------------------------------------------------
__global__ __launch_bounds__(256) void ffn2_kernel(
    const float* __restrict__ ff, const float* __restrict__ w2,
    float* __restrict__ p0, float* __restrict__ p1)
{
  __shared__ float As[16][68];
  __shared__ float Bs[16][68];
  const int tid = threadIdx.x;
  const int m0 = blockIdx.x * 64;
  const int n0 = blockIdx.y * 64;
  const int kbase = blockIdx.z * 1024;
  float* outp = blockIdx.z ? p1 : p0;
  const int tm = (tid & 15) * 4;
  const int tn = (tid >> 4) * 4;
  const int lr = tid >> 4, lc = tid & 15;
  float acc[4][4] = {};
  for (int k0 = 0; k0 < 1024; k0 += 16) {
    #pragma unroll
    for (int r = lr; r < 64; r += 16) {
      As[lc][r] = ff[(size_t)(m0 + r)*2048 + kbase + k0 + lc];
      Bs[lc][r] = w2[(size_t)(n0 + r)*2048 + kbase + k0 + lc];
    }
    __syncthreads();
    #pragma unroll
    for (int k = 0; k < 16; ++k) {
      const float4 a  = *(const float4*)&As[k][tm];
      const float4 bv = *(const float4*)&Bs[k][tn];
      acc[0][0] += a.x*bv.x; acc[0][1] += a.x*bv.y; acc[0][2] += a.x*bv.z; acc[0][3] += a.x*bv.w;
      acc[1][0] += a.y*bv.x; acc[1][1] += a.y*bv.y; acc[1][2] += a.y*bv.z; acc[1][3] += a.y*bv.w;
      acc[2][0] += a.z*bv.x; acc[2][1] += a.z*bv.y; acc[2][2] += a.z*bv.z; acc[2][3] += a.z*bv.w;
      acc[3][0] += a.w*bv.x; acc[3][1] += a.w*bv.y; acc[3][2] += a.w*bv.z; acc[3][3] += a.w*bv.w;
    }
    __syncthreads();
  }
  #pragma unroll
  for (int i = 0; i < 4; ++i) {
    float4 v; v.x = acc[i][0]; v.y = acc[i][1]; v.z = acc[i][2]; v.w = acc[i][3];
    *(float4*)&outp[(m0 + tm + i)*512 + n0 + tn] = v;
  }
}

// ---------------------------------------------------------------------------
// K7: out = LN(x + p0 + p1 + b2) * g2 + be2
// ---------------------------------------------------------------------------
__global__ __launch_bounds__(256) void ln2_kernel(
    const float* __restrict__ p0, const float* __restrict__ p1,
    const float* __restrict__ x, const float* __restrict__ b2,
    const float* __restrict__ g2, const float* __restrict__ be2,
    float* __restrict__ out)
{
  const int bi = blockIdx.x, tid = threadIdx.x;
  const int d0 = tid * 2;
  const float2 a0 = *(const float2*)&p0[bi*512 + d0];
  const float2 a1 = *(const float2*)&p1[bi*512 + d0];
  const float2 xr = *(const float2*)&x [bi*512 + d0];
  const float2 bb = *(const float2*)&b2[d0];
  const float y0 = a0.x + a1.x + bb.x + xr.x;
  const float y1 = a0.y + a1.y + bb.y + xr.y;
  float s1 = y0 + y1, s2 = y0*y0 + y1*y1;
  #pragma unroll
  for (int o = 32; o > 0; o >>= 1) { s1 += __shfl_xor(s1, o, 64); s2 += __shfl_xor(s2, o, 64); }
  __shared__ float r1[4], r2[4];
  const int w = tid >> 6;
  if ((tid & 63) == 0) { r1[w] = s1; r2[w] = s2; }
  __syncthreads();
  const float t1 = r1[0] + r1[1] + r1[2] + r1[3];
  const float t2 = r2[0] + r2[1] + r2[2] + r2[3];
  const float mu  = t1 * (1.f/512.f);
  const float var = t2 * (1.f/512.f) - mu*mu;
  const float rs  = rsqrtf(var + LN_EPS);
  const float2 g  = *(const float2*)&g2 [d0];
  const float2 be = *(const float2*)&be2[d0];
  out[bi*512 + d0]     = (y0 - mu)*rs*g.x + be.x;
  out[bi*512 + d0 + 1] = (y1 - mu)*rs*g.y + be.y;
}

// ---------------------------------------------------------------------------
extern "C" void kernel_launch(void* const* d_in, const int* in_sizes, int n_in,
                              void* d_out, int out_size, void* d_ws, size_t ws_size,
                              hipStream_t stream) {
  const float* src  = (const float*)d_in[0];
  const float* relf = (const float*)d_in[1];
  const float* rel_w = (const float*)d_in[2];
  const float* rel_b = (const float*)d_in[3];
  const float* w1 = (const float*)d_in[4];
  const float* b1 = (const float*)d_in[5];
  const float* w2 = (const float*)d_in[6];
  const float* b2 = (const float*)d_in[7];
  const float* g1  = (const float*)d_in[8];
  const float* be1 = (const float*)d_in[9];
  const float* g2  = (const float*)d_in[10];
  const float* be2 = (const float*)d_in[11];
  float* out = (float*)d_out;

  float* ws = (float*)d_ws;
  // layout (floats); aliases exploit liveness:
  float* qw       = ws;               // [0, 524288)        dead after K2
  float* qb       = ws + 524288;      // [524288, 532480)   dead after K1
  float* S        = ws + 532480;      // [532480, 4726784)  dead after K3
  float* attn_out = ws + 4726784;     // [4726784, 5251072) dead after K4
  float* x        = ws + 5251072;     // [5251072, 5775360) live to end
  float* ff       = S;                // alias: 2097152 <= 4194304, used after S dead
  float* p0       = qw;               // alias: dead qw region
  float* p1       = attn_out;         // alias: dead attn_out region
  // total ws use: 5775360 floats = 23.1 MB

  qw_kernel        <<<1024, 256, 0, stream>>>(src, rel_w, rel_b, qw, qb);
  base_kernel      <<<dim3(16, 8, 8), 256, 0, stream>>>(src, qb, S);
  rel_kernel       <<<dim3(1024, 8), 256, 0, stream>>>(relf, qw, S);
  softmax_pv_kernel<<<dim3(16, 32), 256, 0, stream>>>(S, src, attn_out);
  ln1_kernel       <<<1024, 256, 0, stream>>>(src, attn_out, g1, be1, x);
  ffn1_kernel      <<<dim3(16, 32), 256, 0, stream>>>(x, w1, b1, ff);
  ffn2_kernel      <<<dim3(16, 8, 2), 256, 0, stream>>>(ff, w2, p0, p1);
  ln2_kernel       <<<1024, 256, 0, stream>>>(p0, p1, x, b2, g2, be2, out);
}

// Round 3
// 118.018 us; speedup vs baseline: 3.0005x; 1.9701x over previous
//
#include <hip/hip_runtime.h>
#include <math.h>

#define LN_EPS 1e-5f
// B=2 L=512 D=512 H=8 DH=64 C=64 F=2048
// S layout: S[b,h,i,j] = S[((b*8+h)*512 + i)*512 + j]

typedef __bf16 bf16x8 __attribute__((ext_vector_type(8)));
typedef float f32x4 __attribute__((ext_vector_type(4)));
typedef unsigned short ushort_t;
typedef unsigned int uint_t;

__device__ inline ushort_t f2bf(float f) {
  uint_t u = __float_as_uint(f);
  return (ushort_t)((u + 0x7FFFu + ((u >> 16) & 1u)) >> 16);
}

// ---------------------------------------------------------------------------
// K0: qw[b,i,h,c] = sum_d q[h*64+d]*rel_w[(h*64+d)*64+c] ; qb = q . rel_b (per head)
// ---------------------------------------------------------------------------
__global__ __launch_bounds__(256) void qw_kernel(
    const float* __restrict__ src, const float* __restrict__ rel_w,
    const float* __restrict__ rel_b, float* __restrict__ qw, float* __restrict__ qb)
{
  const int bi = blockIdx.x;     // b*512 + i
  const int tid = threadIdx.x;
  __shared__ float q_sh[512];
  q_sh[tid]       = src[bi*512 + tid];
  q_sh[tid + 256] = src[bi*512 + tid + 256];
  __syncthreads();
  for (int idx = tid; idx < 512; idx += 256) {
    const int h = idx >> 6, c = idx & 63;
    float s = 0.f;
    #pragma unroll 8
    for (int d = 0; d < 64; ++d)
      s = fmaf(q_sh[h*64+d], rel_w[(h*64+d)*64 + c], s);
    qw[bi*512 + idx] = s;
  }
  if (tid < 8) {
    float s = 0.f;
    for (int d = 0; d < 64; ++d) s = fmaf(q_sh[tid*64+d], rel_b[tid*64+d], s);
    qb[bi*8 + tid] = s;
  }
}

// ---------------------------------------------------------------------------
// K1: S[b,h,i,j] = scale * q_i . q_j (head slice) + qb[b,i,h]
// ---------------------------------------------------------------------------
__global__ __launch_bounds__(256) void base_kernel(
    const float* __restrict__ src, const float* __restrict__ qb,
    float* __restrict__ S)
{
  const int bh = blockIdx.x, it = blockIdx.y, jt = blockIdx.z;
  const int b = bh >> 3, h = bh & 7;
  const int i0 = it*64, j0 = jt*64;
  const int tid = threadIdx.x;
  __shared__ float As[64][68];
  __shared__ float Bs[64][68];
  const float* sb = src + (size_t)b*512*512 + h*64;
  for (int idx = tid; idx < 4096; idx += 256) {
    const int k = idx & 63, m = idx >> 6;
    As[k][m] = sb[(size_t)(i0+m)*512 + k] * 0.125f;
    Bs[k][m] = sb[(size_t)(j0+m)*512 + k];
  }
  __syncthreads();
  const int tm = (tid & 15)*4, tn = (tid >> 4)*4;
  float acc[4][4] = {};
  #pragma unroll
  for (int k = 0; k < 64; ++k) {
    const float4 a  = *(const float4*)&As[k][tm];
    const float4 bv = *(const float4*)&Bs[k][tn];
    acc[0][0] += a.x*bv.x; acc[0][1] += a.x*bv.y; acc[0][2] += a.x*bv.z; acc[0][3] += a.x*bv.w;
    acc[1][0] += a.y*bv.x; acc[1][1] += a.y*bv.y; acc[1][2] += a.y*bv.z; acc[1][3] += a.y*bv.w;
    acc[2][0] += a.z*bv.x; acc[2][1] += a.z*bv.y; acc[2][2] += a.z*bv.z; acc[2][3] += a.z*bv.w;
    acc[3][0] += a.w*bv.x; acc[3][1] += a.w*bv.y; acc[3][2] += a.w*bv.z; acc[3][3] += a.w*bv.w;
  }
  float* Sp = S + ((size_t)bh*512 + i0)*512 + j0;
  #pragma unroll
  for (int ii = 0; ii < 4; ++ii) {
    const float qbv = qb[(size_t)(b*512 + i0 + tm + ii)*8 + h];
    float4 v;
    v.x = acc[ii][0] + qbv; v.y = acc[ii][1] + qbv;
    v.z = acc[ii][2] + qbv; v.w = acc[ii][3] + qbv;
    *(float4*)&Sp[(size_t)(tm+ii)*512 + tn] = v;
  }
}

// ---------------------------------------------------------------------------
// K2: S[b,h,i,j] += sum_c RF[b,i,j,c] * qw[b,i,h,c]
// ---------------------------------------------------------------------------
__global__ __launch_bounds__(256) void rel_kernel(
    const float* __restrict__ rel, const float* __restrict__ qw,
    float* __restrict__ S)
{
  const int bi = blockIdx.x, jt = blockIdx.y;
  const int b = bi >> 9, i = bi & 511;
  const int j0 = jt * 64;
  const int tid = threadIdx.x;
  __shared__ float RF[64*65];
  __shared__ float QW[512];
  QW[tid]       = qw[(size_t)bi*512 + tid];
  QW[tid + 256] = qw[(size_t)bi*512 + tid + 256];
  const float4* rg = (const float4*)(rel + ((size_t)bi*512 + j0)*64);
  #pragma unroll
  for (int p = 0; p < 4; ++p) {
    const int f = p*256 + tid;
    const float4 v = rg[f];
    const int j = f >> 4, c = (f & 15)*4;
    float* dst = &RF[j*65 + c];
    dst[0]=v.x; dst[1]=v.y; dst[2]=v.z; dst[3]=v.w;
  }
  __syncthreads();
  const int j = tid & 63, hg = tid >> 6;
  const float* rfj = &RF[j*65];
  const float* q0 = &QW[hg*64];
  const float* q1 = &QW[(hg+4)*64];
  float a0 = 0.f, a1 = 0.f;
  #pragma unroll
  for (int c = 0; c < 64; ++c) {
    const float r = rfj[c];
    a0 = fmaf(r, q0[c], a0);
    a1 = fmaf(r, q1[c], a1);
  }
  const size_t base = ((size_t)(b*8+hg)*512 + i)*512 + j0 + j;
  S[base] += a0;
  S[base + (size_t)4*512*512] += a1;
}

// ---------------------------------------------------------------------------
// K3: softmax rows of S + PV -> attn_out
// ---------------------------------------------------------------------------
__global__ __launch_bounds__(256) void softmax_pv_kernel(
    const float* __restrict__ S, const float* __restrict__ src,
    float* __restrict__ attn_out)
{
  const int bh = blockIdx.x, it = blockIdx.y;
  const int b = bh >> 3, h = bh & 7;
  const int i0 = it * 16;
  const int tid = threadIdx.x;
  const int lane = tid & 63, w = tid >> 6;
  __shared__ float Pt[512*20];

  #pragma unroll
  for (int k = 0; k < 4; ++k) {
    const int il = w*4 + k;
    const float* Srow = S + ((size_t)bh*512 + i0 + il)*512;
    float v[8];
    float m = -1e30f;
    #pragma unroll
    for (int r = 0; r < 8; ++r) { v[r] = Srow[lane + 64*r]; m = fmaxf(m, v[r]); }
    #pragma unroll
    for (int o = 32; o > 0; o >>= 1) m = fmaxf(m, __shfl_xor(m, o, 64));
    float s = 0.f;
    #pragma unroll
    for (int r = 0; r < 8; ++r) { v[r] = __expf(v[r] - m); s += v[r]; }
    #pragma unroll
    for (int o = 32; o > 0; o >>= 1) s += __shfl_xor(s, o, 64);
    const float inv = 1.f / s;
    #pragma unroll
    for (int r = 0; r < 8; ++r) Pt[(lane + 64*r)*20 + il] = v[r] * inv;
  }
  __syncthreads();

  const int d = lane, ig = w;
  const float* V = src + (size_t)b*512*512 + h*64 + d;
  float acc0=0.f, acc1=0.f, acc2=0.f, acc3=0.f;
  #pragma unroll 8
  for (int j = 0; j < 512; ++j) {
    const float vv = V[(size_t)j*512];
    const float4 p = *(const float4*)&Pt[j*20 + ig*4];
    acc0 = fmaf(p.x, vv, acc0); acc1 = fmaf(p.y, vv, acc1);
    acc2 = fmaf(p.z, vv, acc2); acc3 = fmaf(p.w, vv, acc3);
  }
  float* out = attn_out + ((size_t)(b*512) + i0)*512 + h*64 + d;
  out[(size_t)(ig*4+0)*512] = acc0;
  out[(size_t)(ig*4+1)*512] = acc1;
  out[(size_t)(ig*4+2)*512] = acc2;
  out[(size_t)(ig*4+3)*512] = acc3;
}

// ---------------------------------------------------------------------------
// K4: x = LN(src + attn_out) * g1 + be1 ; also emit x in bf16
// ---------------------------------------------------------------------------
__global__ __launch_bounds__(256) void ln1_kernel(
    const float* __restrict__ a, const float* __restrict__ bb,
    const float* __restrict__ g, const float* __restrict__ be,
    float* __restrict__ out, ushort_t* __restrict__ xb)
{
  const int bi = blockIdx.x, tid = threadIdx.x;
  const int d0 = tid * 2;
  const float2 xa = *(const float2*)&a [bi*512 + d0];
  const float2 xv = *(const float2*)&bb[bi*512 + d0];
  const float y0 = xa.x + xv.x;
  const float y1 = xa.y + xv.y;
  float s1 = y0 + y1, s2 = y0*y0 + y1*y1;
  #pragma unroll
  for (int o = 32; o > 0; o >>= 1) { s1 += __shfl_xor(s1, o, 64); s2 += __shfl_xor(s2, o, 64); }
  __shared__ float r1[4], r2[4];
  const int w = tid >> 6;
  if ((tid & 63) == 0) { r1[w] = s1; r2[w] = s2; }
  __syncthreads();
  const float t1 = r1[0] + r1[1] + r1[2] + r1[3];
  const float t2 = r2[0] + r2[1] + r2[2] + r2[3];
  const float mu  = t1 * (1.f/512.f);
  const float var = t2 * (1.f/512.f) - mu*mu;
  const float rs  = rsqrtf(var + LN_EPS);
  const float2 gg = *(const float2*)&g [d0];
  const float2 bv = *(const float2*)&be[d0];
  const float o0 = (y0 - mu)*rs*gg.x + bv.x;
  const float o1 = (y1 - mu)*rs*gg.y + bv.y;
  out[bi*512 + d0]     = o0;
  out[bi*512 + d0 + 1] = o1;
  *(uint_t*)&xb[bi*512 + d0] = (uint_t)f2bf(o0) | ((uint_t)f2bf(o1) << 16);
}

// ---------------------------------------------------------------------------
// K5: fp32 -> bf16 conversion (for w1, w2)
// ---------------------------------------------------------------------------
__global__ __launch_bounds__(256) void conv_kernel(
    const float* __restrict__ in, ushort_t* __restrict__ out, int n)
{
  const int i = (blockIdx.x*256 + threadIdx.x)*8;
  if (i >= n) return;
  const float4 a = *(const float4*)(in + i);
  const float4 b = *(const float4*)(in + i + 4);
  uint4 v;
  v.x = (uint_t)f2bf(a.x) | ((uint_t)f2bf(a.y) << 16);
  v.y = (uint_t)f2bf(a.z) | ((uint_t)f2bf(a.w) << 16);
  v.z = (uint_t)f2bf(b.x) | ((uint_t)f2bf(b.y) << 16);
  v.w = (uint_t)f2bf(b.z) | ((uint_t)f2bf(b.w) << 16);
  *(uint4*)(out + i) = v;
}

// ---------------------------------------------------------------------------
// K6: MFMA GEMM  ff = leaky_relu(xb @ w1b^T + b1), bf16 out
// BM=128 BN=64 BK=64; 4 waves 2x2; wave tile 64x32 (4x2 frags)
// grid (8, 32)
// ---------------------------------------------------------------------------
__global__ __launch_bounds__(256) void gemm_ffn1(
    const ushort_t* __restrict__ A,   // [1024][512] bf16 bits
    const ushort_t* __restrict__ B,   // [2048][512] bf16 bits
    const float* __restrict__ bias, ushort_t* __restrict__ C)  // [1024][2048]
{
  __shared__ ushort_t Asm[128*64];
  __shared__ ushort_t Bsm[64*64];
  const int tid = threadIdx.x;
  const int m0 = blockIdx.x * 128, n0 = blockIdx.y * 64;
  const int lane = tid & 63;
  const int wr = (tid >> 7) & 1, wc = (tid >> 6) & 1;

  const int arow = tid >> 1, ar7 = arow & 7;
  const int acb  = (tid & 1) * 4;
  const int brow = tid >> 2, br7 = brow & 7;
  const int bcb  = (tid & 3) * 2;

  f32x4 acc[4][2] = {};
  for (int kt = 0; kt < 8; ++kt) {
    const uint4* ga = (const uint4*)(A + (size_t)(m0 + arow)*512 + kt*64);
    const uint4 av0 = ga[acb+0], av1 = ga[acb+1], av2 = ga[acb+2], av3 = ga[acb+3];
    const uint4* gb = (const uint4*)(B + (size_t)(n0 + brow)*512 + kt*64);
    const uint4 bv0 = gb[bcb+0], bv1 = gb[bcb+1];
    __syncthreads();
    *(uint4*)&Asm[arow*64 + (((acb+0) ^ ar7) << 3)] = av0;
    *(uint4*)&Asm[arow*64 + (((acb+1) ^ ar7) << 3)] = av1;
    *(uint4*)&Asm[arow*64 + (((acb+2) ^ ar7) << 3)] = av2;
    *(uint4*)&Asm[arow*64 + (((acb+3) ^ ar7) << 3)] = av3;
    *(uint4*)&Bsm[brow*64 + (((bcb+0) ^ br7) << 3)] = bv0;
    *(uint4*)&Bsm[brow*64 + (((bcb+1) ^ br7) << 3)] = bv1;
    __syncthreads();
    #pragma unroll
    for (int kk = 0; kk < 2; ++kk) {
      bf16x8 af[4], bfm[2];
      #pragma unroll
      for (int fm = 0; fm < 4; ++fm) {
        const int r = wr*64 + fm*16 + (lane & 15);
        const int c = (kk*4 + (lane >> 4)) ^ (r & 7);
        af[fm] = *(const bf16x8*)&Asm[r*64 + c*8];
      }
      #pragma unroll
      for (int fn = 0; fn < 2; ++fn) {
        const int r = wc*32 + fn*16 + (lane & 15);
        const int c = (kk*4 + (lane >> 4)) ^ (r & 7);
        bfm[fn] = *(const bf16x8*)&Bsm[r*64 + c*8];
      }
      #pragma unroll
      for (int fm = 0; fm < 4; ++fm)
        #pragma unroll
        for (int fn = 0; fn < 2; ++fn)
          acc[fm][fn] = __builtin_amdgcn_mfma_f32_16x16x32_bf16(af[fm], bfm[fn], acc[fm][fn], 0, 0, 0);
    }
  }
  #pragma unroll
  for (int fn = 0; fn < 2; ++fn) {
    const int col = n0 + wc*32 + fn*16 + (lane & 15);
    const float bb = bias[col];
    #pragma unroll
    for (int fm = 0; fm < 4; ++fm) {
      #pragma unroll
      for (int r = 0; r < 4; ++r) {
        const int row = m0 + wr*64 + fm*16 + (lane >> 4)*4 + r;
        float t = acc[fm][fn][r] + bb;
        t = t > 0.f ? t : 0.01f*t;
        C[(size_t)row*2048 + col] = f2bf(t);
      }
    }
  }
}

// ---------------------------------------------------------------------------
// K7: MFMA GEMM  p[z] = ff @ w2b^T over K-slice z*512..+512, fp32 partials
// grid (8, 8, 4)
// ---------------------------------------------------------------------------
__global__ __launch_bounds__(256) void gemm_ffn2(
    const ushort_t* __restrict__ A,   // ff [1024][2048] bf16 bits
    const ushort_t* __restrict__ B,   // w2b [512][2048] bf16 bits
    float* __restrict__ P)            // [4][1024][512]
{
  __shared__ ushort_t Asm[128*64];
  __shared__ ushort_t Bsm[64*64];
  const int tid = threadIdx.x;
  const int m0 = blockIdx.x * 128, n0 = blockIdx.y * 64;
  const int kbase = blockIdx.z * 512;
  float* outp = P + (size_t)blockIdx.z * 524288;
  const int lane = tid & 63;
  const int wr = (tid >> 7) & 1, wc = (tid >> 6) & 1;

  const int arow = tid >> 1, ar7 = arow & 7;
  const int acb  = (tid & 1) * 4;
  const int brow = tid >> 2, br7 = brow & 7;
  const int bcb  = (tid & 3) * 2;

  f32x4 acc[4][2] = {};
  for (int kt = 0; kt < 8; ++kt) {
    const uint4* ga = (const uint4*)(A + (size_t)(m0 + arow)*2048 + kbase + kt*64);
    const uint4 av0 = ga[acb+0], av1 = ga[acb+1], av2 = ga[acb+2], av3 = ga[acb+3];
    const uint4* gb = (const uint4*)(B + (size_t)(n0 + brow)*2048 + kbase + kt*64);
    const uint4 bv0 = gb[bcb+0], bv1 = gb[bcb+1];
    __syncthreads();
    *(uint4*)&Asm[arow*64 + (((acb+0) ^ ar7) << 3)] = av0;
    *(uint4*)&Asm[arow*64 + (((acb+1) ^ ar7) << 3)] = av1;
    *(uint4*)&Asm[arow*64 + (((acb+2) ^ ar7) << 3)] = av2;
    *(uint4*)&Asm[arow*64 + (((acb+3) ^ ar7) << 3)] = av3;
    *(uint4*)&Bsm[brow*64 + (((bcb+0) ^ br7) << 3)] = bv0;
    *(uint4*)&Bsm[brow*64 + (((bcb+1) ^ br7) << 3)] = bv1;
    __syncthreads();
    #pragma unroll
    for (int kk = 0; kk < 2; ++kk) {
      bf16x8 af[4], bfm[2];
      #pragma unroll
      for (int fm = 0; fm < 4; ++fm) {
        const int r = wr*64 + fm*16 + (lane & 15);
        const int c = (kk*4 + (lane >> 4)) ^ (r & 7);
        af[fm] = *(const bf16x8*)&Asm[r*64 + c*8];
      }
      #pragma unroll
      for (int fn = 0; fn < 2; ++fn) {
        const int r = wc*32 + fn*16 + (lane & 15);
        const int c = (kk*4 + (lane >> 4)) ^ (r & 7);
        bfm[fn] = *(const bf16x8*)&Bsm[r*64 + c*8];
      }
      #pragma unroll
      for (int fm = 0; fm < 4; ++fm)
        #pragma unroll
        for (int fn = 0; fn < 2; ++fn)
          acc[fm][fn] = __builtin_amdgcn_mfma_f32_16x16x32_bf16(af[fm], bfm[fn], acc[fm][fn], 0, 0, 0);
    }
  }
  #pragma unroll
  for (int fn = 0; fn < 2; ++fn) {
    const int col = n0 + wc*32 + fn*16 + (lane & 15);
    #pragma unroll
    for (int fm = 0; fm < 4; ++fm) {
      #pragma unroll
      for (int r = 0; r < 4; ++r) {
        const int row = m0 + wr*64 + fm*16 + (lane >> 4)*4 + r;
        outp[(size_t)row*512 + col] = acc[fm][fn][r];
      }
    }
  }
}

// ---------------------------------------------------------------------------
// K8: out = LN(x + p0+p1+p2+p3 + b2) * g2 + be2
// ---------------------------------------------------------------------------
__global__ __launch_bounds__(256) void ln2_kernel(
    const float* __restrict__ p, const float* __restrict__ x,
    const float* __restrict__ b2, const float* __restrict__ g2,
    const float* __restrict__ be2, float* __restrict__ out)
{
  const int bi = blockIdx.x, tid = threadIdx.x;
  const int d0 = tid * 2;
  const float2 a0 = *(const float2*)&p[bi*512 + d0];
  const float2 a1 = *(const float2*)&p[524288 + bi*512 + d0];
  const float2 a2 = *(const float2*)&p[1048576 + bi*512 + d0];
  const float2 a3 = *(const float2*)&p[1572864 + bi*512 + d0];
  const float2 xr = *(const float2*)&x [bi*512 + d0];
  const float2 bb = *(const float2*)&b2[d0];
  const float y0 = a0.x + a1.x + a2.x + a3.x + bb.x + xr.x;
  const float y1 = a0.y + a1.y + a2.y + a3.y + bb.y + xr.y;
  float s1 = y0 + y1, s2 = y0*y0 + y1*y1;
  #pragma unroll
  for (int o = 32; o > 0; o >>= 1) { s1 += __shfl_xor(s1, o, 64); s2 += __shfl_xor(s2, o, 64); }
  __shared__ float r1[4], r2[4];
  const int w = tid >> 6;
  if ((tid & 63) == 0) { r1[w] = s1; r2[w] = s2; }
  __syncthreads();
  const float t1 = r1[0] + r1[1] + r1[2] + r1[3];
  const float t2 = r2[0] + r2[1] + r2[2] + r2[3];
  const float mu  = t1 * (1.f/512.f);
  const float var = t2 * (1.f/512.f) - mu*mu;
  const float rs  = rsqrtf(var + LN_EPS);
  const float2 g  = *(const float2*)&g2 [d0];
  const float2 be = *(const float2*)&be2[d0];
  out[bi*512 + d0]     = (y0 - mu)*rs*g.x + be.x;
  out[bi*512 + d0 + 1] = (y1 - mu)*rs*g.y + be.y;
}

// ---------------------------------------------------------------------------
extern "C" void kernel_launch(void* const* d_in, const int* in_sizes, int n_in,
                              void* d_out, int out_size, void* d_ws, size_t ws_size,
                              hipStream_t stream) {
  const float* src  = (const float*)d_in[0];
  const float* relf = (const float*)d_in[1];
  const float* rel_w = (const float*)d_in[2];
  const float* rel_b = (const float*)d_in[3];
  const float* w1 = (const float*)d_in[4];
  const float* b1 = (const float*)d_in[5];
  const float* w2 = (const float*)d_in[6];
  const float* b2 = (const float*)d_in[7];
  const float* g1  = (const float*)d_in[8];
  const float* be1 = (const float*)d_in[9];
  const float* g2  = (const float*)d_in[10];
  const float* be2 = (const float*)d_in[11];
  float* out = (float*)d_out;

  float* ws = (float*)d_ws;
  // float-offset layout (23.1 MB total, same footprint as round 2):
  float*    qw  = ws;                          // [0, 524288)       dead after rel
  float*    qb  = ws + 524288;                 // [524288, 532480)
  float*    S   = ws + 532480;                 // [532480, 4726784) dead after softmax_pv
  float*    attn_out = ws + 4726784;           // dead after ln1
  float*    x   = ws + 5251072;                // [5251072, 5775360)
  ushort_t* ffb = (ushort_t*)S;                // 2M bf16 = 1048576 f-slots, in dead S
  float*    p   = S + 1048576;                 // 4 x 524288 f partials, in dead S
  ushort_t* xb  = (ushort_t*)(S + 3145728);    // 512K bf16 = 262144 f-slots, in dead S
  ushort_t* w1b = (ushort_t*)qw;               // 1M bf16 in dead qw
  ushort_t* w2b = (ushort_t*)attn_out;         // 1M bf16 in dead attn_out

  qw_kernel        <<<1024, 256, 0, stream>>>(src, rel_w, rel_b, qw, qb);
  base_kernel      <<<dim3(16, 8, 8), 256, 0, stream>>>(src, qb, S);
  rel_kernel       <<<dim3(1024, 8), 256, 0, stream>>>(relf, qw, S);
  softmax_pv_kernel<<<dim3(16, 32), 256, 0, stream>>>(S, src, attn_out);
  ln1_kernel       <<<1024, 256, 0, stream>>>(src, attn_out, g1, be1, x, xb);
  conv_kernel      <<<512, 256, 0, stream>>>(w1, w1b, 1048576);
  gemm_ffn1        <<<dim3(8, 32), 256, 0, stream>>>(xb, w1b, b1, ffb);
  conv_kernel      <<<512, 256, 0, stream>>>(w2, w2b, 1048576);
  gemm_ffn2        <<<dim3(8, 8, 4), 256, 0, stream>>>(ffb, w2b, p);
  ln2_kernel       <<<1024, 256, 0, stream>>>(p, x, b2, g2, be2, out);
}

// Round 4
// 101.229 us; speedup vs baseline: 3.4981x; 1.1659x over previous
//
#include <hip/hip_runtime.h>
#include <math.h>

#define LN_EPS 1e-5f
// B=2 L=512 D=512 H=8 DH=64 C=64 F=2048
// Sb layout (bf16): Sb[b,h,i,j] = Sb[((b*8+h)*512 + i)*512 + j]

typedef __bf16 bf16x8 __attribute__((ext_vector_type(8)));
typedef unsigned short u16x8 __attribute__((ext_vector_type(8)));
typedef float f32x4 __attribute__((ext_vector_type(4)));
typedef unsigned short ushort_t;
typedef unsigned int uint_t;

__device__ inline ushort_t f2bf(float f) {
  uint_t u = __float_as_uint(f);
  return (ushort_t)((u + 0x7FFFu + ((u >> 16) & 1u)) >> 16);
}
__device__ inline float bf2f(ushort_t b) {
  return __uint_as_float(((uint_t)b) << 16);
}
__device__ inline bf16x8 cvt8(float4 a, float4 b) {
  u16x8 u;
  u[0]=f2bf(a.x); u[1]=f2bf(a.y); u[2]=f2bf(a.z); u[3]=f2bf(a.w);
  u[4]=f2bf(b.x); u[5]=f2bf(b.y); u[6]=f2bf(b.z); u[7]=f2bf(b.w);
  return __builtin_bit_cast(bf16x8, u);
}

// ---------------------------------------------------------------------------
// K0: qwb[b,i,h,c] = bf16( sum_d q[h*64+d]*rel_w[(h*64+d)*64+c] );
//     qb[b,i,h] = q . rel_b (head slice); srcb = bf16(src)
// ---------------------------------------------------------------------------
__global__ __launch_bounds__(256) void qw_kernel(
    const float* __restrict__ src, const float* __restrict__ rel_w,
    const float* __restrict__ rel_b, ushort_t* __restrict__ qwb,
    float* __restrict__ qb, ushort_t* __restrict__ srcb)
{
  const int bi = blockIdx.x;     // b*512 + i
  const int tid = threadIdx.x;
  __shared__ float q_sh[512];
  q_sh[tid]       = src[bi*512 + tid];
  q_sh[tid + 256] = src[bi*512 + tid + 256];
  __syncthreads();
  // srcb: pack 2 bf16 per thread
  {
    const float a = q_sh[2*tid], b = q_sh[2*tid+1];
    *(uint_t*)&srcb[(size_t)bi*512 + 2*tid] = (uint_t)f2bf(a) | ((uint_t)f2bf(b) << 16);
  }
  for (int idx = tid; idx < 512; idx += 256) {
    const int h = idx >> 6, c = idx & 63;
    float s = 0.f;
    #pragma unroll 8
    for (int d = 0; d < 64; ++d)
      s = fmaf(q_sh[h*64+d], rel_w[(h*64+d)*64 + c], s);
    qwb[(size_t)bi*512 + idx] = f2bf(s);
  }
  if (tid < 8) {
    float s = 0.f;
    for (int d = 0; d < 64; ++d) s = fmaf(q_sh[tid*64+d], rel_b[tid*64+d], s);
    qb[bi*8 + tid] = s;
  }
}

// ---------------------------------------------------------------------------
// K1: MFMA rel scores: Sb[b,h,i,j] = bf16( sum_c RF[b,i,j,c]*qw[h,c] + qb[h] )
// grid (bi=1024, jh=2); block = 4 waves, each wave 4 j-tiles of 16
// MFMA 16x16x32: A = RF[j,c] (M=j rows), B = qw[h,c] (N=h cols, 8 valid)
// ---------------------------------------------------------------------------
__global__ __launch_bounds__(256) void rel_kernel(
    const float* __restrict__ rel, const ushort_t* __restrict__ qwb,
    const float* __restrict__ qb, ushort_t* __restrict__ Sb)
{
  const int bi = blockIdx.x, jh = blockIdx.y;
  const int b = bi >> 9, i = bi & 511;
  const int tid = threadIdx.x, lane = tid & 63, w = tid >> 6;
  const int hl = lane & 15;          // D col (head), valid < 8
  const int kc = lane >> 4;          // k-chunk 0..3
  const int h  = hl & 7;

  const bf16x8 b0 = *(const bf16x8*)&qwb[(size_t)bi*512 + h*64 + kc*8];
  const bf16x8 b1 = *(const bf16x8*)&qwb[(size_t)bi*512 + h*64 + 32 + kc*8];
  const float qbv = qb[bi*8 + h];

  #pragma unroll
  for (int t = 0; t < 4; ++t) {
    const int j0 = jh*256 + (t*4 + w)*16;
    const int j  = j0 + hl;                  // A row
    const float* rf = rel + ((size_t)bi*512 + j)*64 + kc*8;
    const float4 x0 = *(const float4*)rf;
    const float4 x1 = *(const float4*)(rf + 4);
    const float4 y0 = *(const float4*)(rf + 32);
    const float4 y1 = *(const float4*)(rf + 36);
    const bf16x8 a0 = cvt8(x0, x1);
    const bf16x8 a1 = cvt8(y0, y1);
    f32x4 acc = {0.f, 0.f, 0.f, 0.f};
    acc = __builtin_amdgcn_mfma_f32_16x16x32_bf16(a0, b0, acc, 0, 0, 0);
    acc = __builtin_amdgcn_mfma_f32_16x16x32_bf16(a1, b1, acc, 0, 0, 0);
    if (hl < 8) {
      // D row = kc*4 + r  -> j_out = j0 + kc*4 + r (4 consecutive)
      const float v0 = acc[0] + qbv, v1 = acc[1] + qbv;
      const float v2 = acc[2] + qbv, v3 = acc[3] + qbv;
      uint2 pk;
      pk.x = (uint_t)f2bf(v0) | ((uint_t)f2bf(v1) << 16);
      pk.y = (uint_t)f2bf(v2) | ((uint_t)f2bf(v3) << 16);
      *(uint2*)&Sb[((size_t)(b*8+h)*512 + i)*512 + j0 + kc*4] = pk;
    }
  }
}

// ---------------------------------------------------------------------------
// K2: per (bh, it=16 rows): base scores (MFMA, bf16 src) -> LDS;
//     softmax( 0.125*base + Sb ) -> Pt; PV (fp32) -> attn_out
// ---------------------------------------------------------------------------
__global__ __launch_bounds__(256) void softmax_pv_kernel(
    const ushort_t* __restrict__ Sb, const ushort_t* __restrict__ srcb,
    const float* __restrict__ src, float* __restrict__ attn_out)
{
  const int bh = blockIdx.x, it = blockIdx.y;
  const int b = bh >> 3, h = bh & 7;
  const int i0 = it * 16;
  const int tid = threadIdx.x;
  const int lane = tid & 63, w = tid >> 6;
  __shared__ float Ssm[16][516];
  __shared__ float Pt[512*20];

  // ---- Phase A: base scores Q.K^T via MFMA ----
  {
    const int il = lane & 15, kc = lane >> 4;
    const bf16x8 aq0 = *(const bf16x8*)&srcb[(size_t)(b*512 + i0 + il)*512 + h*64 + kc*8];
    const bf16x8 aq1 = *(const bf16x8*)&srcb[(size_t)(b*512 + i0 + il)*512 + h*64 + 32 + kc*8];
    #pragma unroll
    for (int t = 0; t < 8; ++t) {
      const int jt = t*4 + w;
      const int j  = jt*16 + il;             // B col
      const bf16x8 bk0 = *(const bf16x8*)&srcb[(size_t)(b*512 + j)*512 + h*64 + kc*8];
      const bf16x8 bk1 = *(const bf16x8*)&srcb[(size_t)(b*512 + j)*512 + h*64 + 32 + kc*8];
      f32x4 acc = {0.f, 0.f, 0.f, 0.f};
      acc = __builtin_amdgcn_mfma_f32_16x16x32_bf16(aq0, bk0, acc, 0, 0, 0);
      acc = __builtin_amdgcn_mfma_f32_16x16x32_bf16(aq1, bk1, acc, 0, 0, 0);
      #pragma unroll
      for (int r = 0; r < 4; ++r) Ssm[kc*4 + r][jt*16 + il] = acc[r];
    }
  }
  __syncthreads();

  // ---- Phase B: softmax rows ----
  #pragma unroll
  for (int k = 0; k < 4; ++k) {
    const int row = w*4 + k;
    const ushort_t* Srow = Sb + ((size_t)bh*512 + i0 + row)*512;
    float v[8];
    float m = -1e30f;
    #pragma unroll
    for (int r = 0; r < 8; ++r) {
      v[r] = Ssm[row][lane + 64*r]*0.125f + bf2f(Srow[lane + 64*r]);
      m = fmaxf(m, v[r]);
    }
    #pragma unroll
    for (int o = 32; o > 0; o >>= 1) m = fmaxf(m, __shfl_xor(m, o, 64));
    float s = 0.f;
    #pragma unroll
    for (int r = 0; r < 8; ++r) { v[r] = __expf(v[r] - m); s += v[r]; }
    #pragma unroll
    for (int o = 32; o > 0; o >>= 1) s += __shfl_xor(s, o, 64);
    const float inv = 1.f / s;
    #pragma unroll
    for (int r = 0; r < 8; ++r) Pt[(lane + 64*r)*20 + row] = v[r] * inv;
  }
  __syncthreads();

  // ---- Phase C: PV (fp32) ----
  {
    const int d = lane, ig = w;
    const float* V = src + (size_t)b*512*512 + h*64 + d;
    float acc0=0.f, acc1=0.f, acc2=0.f, acc3=0.f;
    #pragma unroll 8
    for (int j = 0; j < 512; ++j) {
      const float vv = V[(size_t)j*512];
      const float4 p = *(const float4*)&Pt[j*20 + ig*4];
      acc0 = fmaf(p.x, vv, acc0); acc1 = fmaf(p.y, vv, acc1);
      acc2 = fmaf(p.z, vv, acc2); acc3 = fmaf(p.w, vv, acc3);
    }
    float* out = attn_out + ((size_t)(b*512) + i0)*512 + h*64 + d;
    out[(size_t)(ig*4+0)*512] = acc0;
    out[(size_t)(ig*4+1)*512] = acc1;
    out[(size_t)(ig*4+2)*512] = acc2;
    out[(size_t)(ig*4+3)*512] = acc3;
  }
}

// ---------------------------------------------------------------------------
// K3: x = LN(src + attn_out) * g1 + be1 ; also emit x in bf16
// ---------------------------------------------------------------------------
__global__ __launch_bounds__(256) void ln1_kernel(
    const float* __restrict__ a, const float* __restrict__ bb,
    const float* __restrict__ g, const float* __restrict__ be,
    float* __restrict__ out, ushort_t* __restrict__ xb)
{
  const int bi = blockIdx.x, tid = threadIdx.x;
  const int d0 = tid * 2;
  const float2 xa = *(const float2*)&a [bi*512 + d0];
  const float2 xv = *(const float2*)&bb[bi*512 + d0];
  const float y0 = xa.x + xv.x;
  const float y1 = xa.y + xv.y;
  float s1 = y0 + y1, s2 = y0*y0 + y1*y1;
  #pragma unroll
  for (int o = 32; o > 0; o >>= 1) { s1 += __shfl_xor(s1, o, 64); s2 += __shfl_xor(s2, o, 64); }
  __shared__ float r1[4], r2[4];
  const int w = tid >> 6;
  if ((tid & 63) == 0) { r1[w] = s1; r2[w] = s2; }
  __syncthreads();
  const float t1 = r1[0] + r1[1] + r1[2] + r1[3];
  const float t2 = r2[0] + r2[1] + r2[2] + r2[3];
  const float mu  = t1 * (1.f/512.f);
  const float var = t2 * (1.f/512.f) - mu*mu;
  const float rs  = rsqrtf(var + LN_EPS);
  const float2 gg = *(const float2*)&g [d0];
  const float2 bv = *(const float2*)&be[d0];
  const float o0 = (y0 - mu)*rs*gg.x + bv.x;
  const float o1 = (y1 - mu)*rs*gg.y + bv.y;
  out[bi*512 + d0]     = o0;
  out[bi*512 + d0 + 1] = o1;
  *(uint_t*)&xb[bi*512 + d0] = (uint_t)f2bf(o0) | ((uint_t)f2bf(o1) << 16);
}

// ---------------------------------------------------------------------------
// K4: fp32 -> bf16 conversion (for w1, w2)
// ---------------------------------------------------------------------------
__global__ __launch_bounds__(256) void conv_kernel(
    const float* __restrict__ in, ushort_t* __restrict__ out, int n)
{
  const int i = (blockIdx.x*256 + threadIdx.x)*8;
  if (i >= n) return;
  const float4 a = *(const float4*)(in + i);
  const float4 b = *(const float4*)(in + i + 4);
  uint4 v;
  v.x = (uint_t)f2bf(a.x) | ((uint_t)f2bf(a.y) << 16);
  v.y = (uint_t)f2bf(a.z) | ((uint_t)f2bf(a.w) << 16);
  v.z = (uint_t)f2bf(b.x) | ((uint_t)f2bf(b.y) << 16);
  v.w = (uint_t)f2bf(b.z) | ((uint_t)f2bf(b.w) << 16);
  *(uint4*)(out + i) = v;
}

// ---------------------------------------------------------------------------
// K5: MFMA GEMM  ff = leaky_relu(xb @ w1b^T + b1), bf16 out
// BM=128 BN=64 BK=64; 4 waves 2x2; wave tile 64x32 (4x2 frags); grid (8,32)
// ---------------------------------------------------------------------------
__global__ __launch_bounds__(256) void gemm_ffn1(
    const ushort_t* __restrict__ A,   // [1024][512] bf16 bits
    const ushort_t* __restrict__ B,   // [2048][512] bf16 bits
    const float* __restrict__ bias, ushort_t* __restrict__ C)  // [1024][2048]
{
  __shared__ ushort_t Asm[128*64];
  __shared__ ushort_t Bsm[64*64];
  const int tid = threadIdx.x;
  const int m0 = blockIdx.x * 128, n0 = blockIdx.y * 64;
  const int lane = tid & 63;
  const int wr = (tid >> 7) & 1, wc = (tid >> 6) & 1;

  const int arow = tid >> 1, ar7 = arow & 7;
  const int acb  = (tid & 1) * 4;
  const int brow = tid >> 2, br7 = brow & 7;
  const int bcb  = (tid & 3) * 2;

  f32x4 acc[4][2] = {};
  for (int kt = 0; kt < 8; ++kt) {
    const uint4* ga = (const uint4*)(A + (size_t)(m0 + arow)*512 + kt*64);
    const uint4 av0 = ga[acb+0], av1 = ga[acb+1], av2 = ga[acb+2], av3 = ga[acb+3];
    const uint4* gb = (const uint4*)(B + (size_t)(n0 + brow)*512 + kt*64);
    const uint4 bv0 = gb[bcb+0], bv1 = gb[bcb+1];
    __syncthreads();
    *(uint4*)&Asm[arow*64 + (((acb+0) ^ ar7) << 3)] = av0;
    *(uint4*)&Asm[arow*64 + (((acb+1) ^ ar7) << 3)] = av1;
    *(uint4*)&Asm[arow*64 + (((acb+2) ^ ar7) << 3)] = av2;
    *(uint4*)&Asm[arow*64 + (((acb+3) ^ ar7) << 3)] = av3;
    *(uint4*)&Bsm[brow*64 + (((bcb+0) ^ br7) << 3)] = bv0;
    *(uint4*)&Bsm[brow*64 + (((bcb+1) ^ br7) << 3)] = bv1;
    __syncthreads();
    #pragma unroll
    for (int kk = 0; kk < 2; ++kk) {
      bf16x8 af[4], bfm[2];
      #pragma unroll
      for (int fm = 0; fm < 4; ++fm) {
        const int r = wr*64 + fm*16 + (lane & 15);
        const int c = (kk*4 + (lane >> 4)) ^ (r & 7);
        af[fm] = *(const bf16x8*)&Asm[r*64 + c*8];
      }
      #pragma unroll
      for (int fn = 0; fn < 2; ++fn) {
        const int r = wc*32 + fn*16 + (lane & 15);
        const int c = (kk*4 + (lane >> 4)) ^ (r & 7);
        bfm[fn] = *(const bf16x8*)&Bsm[r*64 + c*8];
      }
      #pragma unroll
      for (int fm = 0; fm < 4; ++fm)
        #pragma unroll
        for (int fn = 0; fn < 2; ++fn)
          acc[fm][fn] = __builtin_amdgcn_mfma_f32_16x16x32_bf16(af[fm], bfm[fn], acc[fm][fn], 0, 0, 0);
    }
  }
  #pragma unroll
  for (int fn = 0; fn < 2; ++fn) {
    const int col = n0 + wc*32 + fn*16 + (lane & 15);
    const float bb = bias[col];
    #pragma unroll
    for (int fm = 0; fm < 4; ++fm) {
      #pragma unroll
      for (int r = 0; r < 4; ++r) {
        const int row = m0 + wr*64 + fm*16 + (lane >> 4)*4 + r;
        float t = acc[fm][fn][r] + bb;
        t = t > 0.f ? t : 0.01f*t;
        C[(size_t)row*2048 + col] = f2bf(t);
      }
    }
  }
}

// ---------------------------------------------------------------------------
// K6: MFMA GEMM  p[z] = ff @ w2b^T over K-slice z*512..+512, fp32 partials
// grid (8, 8, 4)
// ---------------------------------------------------------------------------
__global__ __launch_bounds__(256) void gemm_ffn2(
    const ushort_t* __restrict__ A,   // ff [1024][2048] bf16 bits
    const ushort_t* __restrict__ B,   // w2b [512][2048] bf16 bits
    float* __restrict__ P)            // [4][1024][512]
{
  __shared__ ushort_t Asm[128*64];
  __shared__ ushort_t Bsm[64*64];
  const int tid = threadIdx.x;
  const int m0 = blockIdx.x * 128, n0 = blockIdx.y * 64;
  const int kbase = blockIdx.z * 512;
  float* outp = P + (size_t)blockIdx.z * 524288;
  const int lane = tid & 63;
  const int wr = (tid >> 7) & 1, wc = (tid >> 6) & 1;

  const int arow = tid >> 1, ar7 = arow & 7;
  const int acb  = (tid & 1) * 4;
  const int brow = tid >> 2, br7 = brow & 7;
  const int bcb  = (tid & 3) * 2;

  f32x4 acc[4][2] = {};
  for (int kt = 0; kt < 8; ++kt) {
    const uint4* ga = (const uint4*)(A + (size_t)(m0 + arow)*2048 + kbase + kt*64);
    const uint4 av0 = ga[acb+0], av1 = ga[acb+1], av2 = ga[acb+2], av3 = ga[acb+3];
    const uint4* gb = (const uint4*)(B + (size_t)(n0 + brow)*2048 + kbase + kt*64);
    const uint4 bv0 = gb[bcb+0], bv1 = gb[bcb+1];
    __syncthreads();
    *(uint4*)&Asm[arow*64 + (((acb+0) ^ ar7) << 3)] = av0;
    *(uint4*)&Asm[arow*64 + (((acb+1) ^ ar7) << 3)] = av1;
    *(uint4*)&Asm[arow*64 + (((acb+2) ^ ar7) << 3)] = av2;
    *(uint4*)&Asm[arow*64 + (((acb+3) ^ ar7) << 3)] = av3;
    *(uint4*)&Bsm[brow*64 + (((bcb+0) ^ br7) << 3)] = bv0;
    *(uint4*)&Bsm[brow*64 + (((bcb+1) ^ br7) << 3)] = bv1;
    __syncthreads();
    #pragma unroll
    for (int kk = 0; kk < 2; ++kk) {
      bf16x8 af[4], bfm[2];
      #pragma unroll
      for (int fm = 0; fm < 4; ++fm) {
        const int r = wr*64 + fm*16 + (lane & 15);
        const int c = (kk*4 + (lane >> 4)) ^ (r & 7);
        af[fm] = *(const bf16x8*)&Asm[r*64 + c*8];
      }
      #pragma unroll
      for (int fn = 0; fn < 2; ++fn) {
        const int r = wc*32 + fn*16 + (lane & 15);
        const int c = (kk*4 + (lane >> 4)) ^ (r & 7);
        bfm[fn] = *(const bf16x8*)&Bsm[r*64 + c*8];
      }
      #pragma unroll
      for (int fm = 0; fm < 4; ++fm)
        #pragma unroll
        for (int fn = 0; fn < 2; ++fn)
          acc[fm][fn] = __builtin_amdgcn_mfma_f32_16x16x32_bf16(af[fm], bfm[fn], acc[fm][fn], 0, 0, 0);
    }
  }
  #pragma unroll
  for (int fn = 0; fn < 2; ++fn) {
    const int col = n0 + wc*32 + fn*16 + (lane & 15);
    #pragma unroll
    for (int fm = 0; fm < 4; ++fm) {
      #pragma unroll
      for (int r = 0; r < 4; ++r) {
        const int row = m0 + wr*64 + fm*16 + (lane >> 4)*4 + r;
        outp[(size_t)row*512 + col] = acc[fm][fn][r];
      }
    }
  }
}

// ---------------------------------------------------------------------------
// K7: out = LN(x + p0+p1+p2+p3 + b2) * g2 + be2
// ---------------------------------------------------------------------------
__global__ __launch_bounds__(256) void ln2_kernel(
    const float* __restrict__ p, const float* __restrict__ x,
    const float* __restrict__ b2, const float* __restrict__ g2,
    const float* __restrict__ be2, float* __restrict__ out)
{
  const int bi = blockIdx.x, tid = threadIdx.x;
  const int d0 = tid * 2;
  const float2 a0 = *(const float2*)&p[bi*512 + d0];
  const float2 a1 = *(const float2*)&p[524288 + bi*512 + d0];
  const float2 a2 = *(const float2*)&p[1048576 + bi*512 + d0];
  const float2 a3 = *(const float2*)&p[1572864 + bi*512 + d0];
  const float2 xr = *(const float2*)&x [bi*512 + d0];
  const float2 bb = *(const float2*)&b2[d0];
  const float y0 = a0.x + a1.x + a2.x + a3.x + bb.x + xr.x;
  const float y1 = a0.y + a1.y + a2.y + a3.y + bb.y + xr.y;
  float s1 = y0 + y1, s2 = y0*y0 + y1*y1;
  #pragma unroll
  for (int o = 32; o > 0; o >>= 1) { s1 += __shfl_xor(s1, o, 64); s2 += __shfl_xor(s2, o, 64); }
  __shared__ float r1[4], r2[4];
  const int w = tid >> 6;
  if ((tid & 63) == 0) { r1[w] = s1; r2[w] = s2; }
  __syncthreads();
  const float t1 = r1[0] + r1[1] + r1[2] + r1[3];
  const float t2 = r2[0] + r2[1] + r2[2] + r2[3];
  const float mu  = t1 * (1.f/512.f);
  const float var = t2 * (1.f/512.f) - mu*mu;
  const float rs  = rsqrtf(var + LN_EPS);
  const float2 g  = *(const float2*)&g2 [d0];
  const float2 be = *(const float2*)&be2[d0];
  out[bi*512 + d0]     = (y0 - mu)*rs*g.x + be.x;
  out[bi*512 + d0 + 1] = (y1 - mu)*rs*g.y + be.y;
}

// ---------------------------------------------------------------------------
extern "C" void kernel_launch(void* const* d_in, const int* in_sizes, int n_in,
                              void* d_out, int out_size, void* d_ws, size_t ws_size,
                              hipStream_t stream) {
  const float* src  = (const float*)d_in[0];
  const float* relf = (const float*)d_in[1];
  const float* rel_w = (const float*)d_in[2];
  const float* rel_b = (const float*)d_in[3];
  const float* w1 = (const float*)d_in[4];
  const float* b1 = (const float*)d_in[5];
  const float* w2 = (const float*)d_in[6];
  const float* b2 = (const float*)d_in[7];
  const float* g1  = (const float*)d_in[8];
  const float* be1 = (const float*)d_in[9];
  const float* g2  = (const float*)d_in[10];
  const float* be2 = (const float*)d_in[11];
  float* out = (float*)d_out;

  float* ws = (float*)d_ws;
  // ws is ~512 MB (poison fill shows 536 MB) — no aliasing needed.
  ushort_t* qwb  = (ushort_t*)(ws);                 // 524288 bf16 -> 262144 f
  float*    qb   = ws + 262144;                     // 8192 f
  ushort_t* srcb = (ushort_t*)(ws + 270336);        // 524288 bf16 -> 262144 f
  ushort_t* Sb   = (ushort_t*)(ws + 532480);        // 4194304 bf16 -> 2097152 f
  float*    attn = ws + 2629632;                    // 524288 f
  float*    x    = ws + 3153920;                    // 524288 f
  ushort_t* xb   = (ushort_t*)(ws + 3678208);       // 262144 f
  ushort_t* w1b  = (ushort_t*)(ws + 3940352);       // 524288 f
  ushort_t* w2b  = (ushort_t*)(ws + 4464640);       // 524288 f
  ushort_t* ffb  = (ushort_t*)(ws + 4988928);       // 1048576 f
  float*    p    = ws + 6037504;                    // 2097152 f

  qw_kernel        <<<1024, 256, 0, stream>>>(src, rel_w, rel_b, qwb, qb, srcb);
  rel_kernel       <<<dim3(1024, 2), 256, 0, stream>>>(relf, qwb, qb, Sb);
  softmax_pv_kernel<<<dim3(16, 32), 256, 0, stream>>>(Sb, srcb, src, attn);
  ln1_kernel       <<<1024, 256, 0, stream>>>(src, attn, g1, be1, x, xb);
  conv_kernel      <<<512, 256, 0, stream>>>(w1, w1b, 1048576);
  gemm_ffn1        <<<dim3(8, 32), 256, 0, stream>>>(xb, w1b, b1, ffb);
  conv_kernel      <<<512, 256, 0, stream>>>(w2, w2b, 1048576);
  gemm_ffn2        <<<dim3(8, 8, 4), 256, 0, stream>>>(ffb, w2b, p);
  ln2_kernel       <<<1024, 256, 0, stream>>>(p, x, b2, g2, be2, out);
}

// Round 5
// 98.881 us; speedup vs baseline: 3.5812x; 1.0238x over previous
//
#include <hip/hip_runtime.h>
#include <math.h>

#define LN_EPS 1e-5f
// B=2 L=512 D=512 H=8 DH=64 C=64 F=2048
// Sb layout (bf16): Sb[b,h,i,j] = Sb[((b*8+h)*512 + i)*512 + j]

typedef __bf16 bf16x8 __attribute__((ext_vector_type(8)));
typedef unsigned short u16x8 __attribute__((ext_vector_type(8)));
typedef float f32x4 __attribute__((ext_vector_type(4)));
typedef unsigned short ushort_t;
typedef unsigned int uint_t;

__device__ inline ushort_t f2bf(float f) {
  uint_t u = __float_as_uint(f);
  return (ushort_t)((u + 0x7FFFu + ((u >> 16) & 1u)) >> 16);
}
__device__ inline float bf2f(ushort_t b) {
  return __uint_as_float(((uint_t)b) << 16);
}
__device__ inline bf16x8 cvt8(float4 a, float4 b) {
  u16x8 u;
  u[0]=f2bf(a.x); u[1]=f2bf(a.y); u[2]=f2bf(a.z); u[3]=f2bf(a.w);
  u[4]=f2bf(b.x); u[5]=f2bf(b.y); u[6]=f2bf(b.z); u[7]=f2bf(b.w);
  return __builtin_bit_cast(bf16x8, u);
}

// ---------------------------------------------------------------------------
// K1 "rel_plus": blocks 0..1023: per (b,i) compute qw/qb in LDS, then
//   Sb[b,h,i,j] = bf16( sum_c RF[b,i,j,c]*qw[h,c] + qb[h] ) via MFMA.
// blocks 1024..1087: convert src->srcb, w1->w1b, w2->w2b (bf16).
// ---------------------------------------------------------------------------
__global__ __launch_bounds__(256) void rel_plus_kernel(
    const float* __restrict__ src, const float* __restrict__ rel_w,
    const float* __restrict__ rel_b, const float* __restrict__ relf,
    const float* __restrict__ w1, const float* __restrict__ w2,
    ushort_t* __restrict__ srcb, ushort_t* __restrict__ w1b,
    ushort_t* __restrict__ w2b, ushort_t* __restrict__ Sb)
{
  const int tid = threadIdx.x;

  if (blockIdx.x >= 1024) {
    // ---- conversion blocks ----
    const int cb = blockIdx.x - 1024;          // 0..63
    const int tglob = cb*256 + tid;            // 0..16383
    // src: 524288 floats = 65536 float8 items
    for (int it = tglob; it < 65536; it += 16384) {
      const int i = it*8;
      const float4 a = *(const float4*)(src + i);
      const float4 b = *(const float4*)(src + i + 4);
      uint4 v;
      v.x = (uint_t)f2bf(a.x) | ((uint_t)f2bf(a.y) << 16);
      v.y = (uint_t)f2bf(a.z) | ((uint_t)f2bf(a.w) << 16);
      v.z = (uint_t)f2bf(b.x) | ((uint_t)f2bf(b.y) << 16);
      v.w = (uint_t)f2bf(b.z) | ((uint_t)f2bf(b.w) << 16);
      *(uint4*)(srcb + i) = v;
    }
    // w1: 1048576 floats = 131072 items
    for (int it = tglob; it < 131072; it += 16384) {
      const int i = it*8;
      const float4 a = *(const float4*)(w1 + i);
      const float4 b = *(const float4*)(w1 + i + 4);
      uint4 v;
      v.x = (uint_t)f2bf(a.x) | ((uint_t)f2bf(a.y) << 16);
      v.y = (uint_t)f2bf(a.z) | ((uint_t)f2bf(a.w) << 16);
      v.z = (uint_t)f2bf(b.x) | ((uint_t)f2bf(b.y) << 16);
      v.w = (uint_t)f2bf(b.z) | ((uint_t)f2bf(b.w) << 16);
      *(uint4*)(w1b + i) = v;
    }
    // w2: 1048576 floats
    for (int it = tglob; it < 131072; it += 16384) {
      const int i = it*8;
      const float4 a = *(const float4*)(w2 + i);
      const float4 b = *(const float4*)(w2 + i + 4);
      uint4 v;
      v.x = (uint_t)f2bf(a.x) | ((uint_t)f2bf(a.y) << 16);
      v.y = (uint_t)f2bf(a.z) | ((uint_t)f2bf(a.w) << 16);
      v.z = (uint_t)f2bf(b.x) | ((uint_t)f2bf(b.y) << 16);
      v.w = (uint_t)f2bf(b.z) | ((uint_t)f2bf(b.w) << 16);
      *(uint4*)(w2b + i) = v;
    }
    return;
  }

  // ---- rel blocks ----
  const int bi = blockIdx.x;           // b*512 + i
  const int b = bi >> 9, i = bi & 511;
  const int lane = tid & 63, w = tid >> 6;

  __shared__ float q_sh[512];
  __shared__ ushort_t qwb_sh[512];
  __shared__ float qb_sh[8];

  q_sh[tid]       = src[bi*512 + tid];
  q_sh[tid + 256] = src[bi*512 + tid + 256];
  __syncthreads();
  for (int idx = tid; idx < 512; idx += 256) {
    const int h = idx >> 6, c = idx & 63;
    float s = 0.f;
    #pragma unroll 8
    for (int d = 0; d < 64; ++d)
      s = fmaf(q_sh[h*64+d], rel_w[(h*64+d)*64 + c], s);
    qwb_sh[idx] = f2bf(s);
  }
  if (tid < 8) {
    float s = 0.f;
    for (int d = 0; d < 64; ++d) s = fmaf(q_sh[tid*64+d], rel_b[tid*64+d], s);
    qb_sh[tid] = s;
  }
  __syncthreads();

  const int hl = lane & 15;          // D col (head), valid < 8
  const int kc = lane >> 4;          // k-chunk 0..3
  const int h  = hl & 7;

  const bf16x8 b0 = *(const bf16x8*)&qwb_sh[h*64 + kc*8];
  const bf16x8 b1 = *(const bf16x8*)&qwb_sh[h*64 + 32 + kc*8];
  const float qbv = qb_sh[h];
  ushort_t* Sp = Sb + ((size_t)(b*8+h)*512 + i)*512;

  #pragma unroll
  for (int t = 0; t < 8; ++t) {
    const int j0 = (t*4 + w)*16;
    const int j  = j0 + hl;                  // A row
    const float* rf = relf + ((size_t)bi*512 + j)*64 + kc*8;
    const float4 x0 = *(const float4*)rf;
    const float4 x1 = *(const float4*)(rf + 4);
    const float4 y0 = *(const float4*)(rf + 32);
    const float4 y1 = *(const float4*)(rf + 36);
    const bf16x8 a0 = cvt8(x0, x1);
    const bf16x8 a1 = cvt8(y0, y1);
    f32x4 acc = {0.f, 0.f, 0.f, 0.f};
    acc = __builtin_amdgcn_mfma_f32_16x16x32_bf16(a0, b0, acc, 0, 0, 0);
    acc = __builtin_amdgcn_mfma_f32_16x16x32_bf16(a1, b1, acc, 0, 0, 0);
    if (hl < 8) {
      const float v0 = acc[0] + qbv, v1 = acc[1] + qbv;
      const float v2 = acc[2] + qbv, v3 = acc[3] + qbv;
      uint2 pk;
      pk.x = (uint_t)f2bf(v0) | ((uint_t)f2bf(v1) << 16);
      pk.y = (uint_t)f2bf(v2) | ((uint_t)f2bf(v3) << 16);
      *(uint2*)&Sp[j0 + kc*4] = pk;
    }
  }
}

// ---------------------------------------------------------------------------
// K2: per (bh, it=16 rows): base scores (MFMA, bf16 src) -> LDS;
//     softmax( 0.125*base + Sb ) -> Pt; PV (fp32) -> attn_out
// ---------------------------------------------------------------------------
__global__ __launch_bounds__(256) void softmax_pv_kernel(
    const ushort_t* __restrict__ Sb, const ushort_t* __restrict__ srcb,
    const float* __restrict__ src, float* __restrict__ attn_out)
{
  const int bh = blockIdx.x, it = blockIdx.y;
  const int b = bh >> 3, h = bh & 7;
  const int i0 = it * 16;
  const int tid = threadIdx.x;
  const int lane = tid & 63, w = tid >> 6;
  __shared__ float Ssm[16][516];
  __shared__ float Pt[512*20];

  // ---- Phase A: base scores Q.K^T via MFMA ----
  {
    const int il = lane & 15, kc = lane >> 4;
    const bf16x8 aq0 = *(const bf16x8*)&srcb[(size_t)(b*512 + i0 + il)*512 + h*64 + kc*8];
    const bf16x8 aq1 = *(const bf16x8*)&srcb[(size_t)(b*512 + i0 + il)*512 + h*64 + 32 + kc*8];
    #pragma unroll
    for (int t = 0; t < 8; ++t) {
      const int jt = t*4 + w;
      const int j  = jt*16 + il;             // B col
      const bf16x8 bk0 = *(const bf16x8*)&srcb[(size_t)(b*512 + j)*512 + h*64 + kc*8];
      const bf16x8 bk1 = *(const bf16x8*)&srcb[(size_t)(b*512 + j)*512 + h*64 + 32 + kc*8];
      f32x4 acc = {0.f, 0.f, 0.f, 0.f};
      acc = __builtin_amdgcn_mfma_f32_16x16x32_bf16(aq0, bk0, acc, 0, 0, 0);
      acc = __builtin_amdgcn_mfma_f32_16x16x32_bf16(aq1, bk1, acc, 0, 0, 0);
      #pragma unroll
      for (int r = 0; r < 4; ++r) Ssm[kc*4 + r][jt*16 + il] = acc[r];
    }
  }
  __syncthreads();

  // ---- Phase B: softmax rows ----
  #pragma unroll
  for (int k = 0; k < 4; ++k) {
    const int row = w*4 + k;
    const ushort_t* Srow = Sb + ((size_t)bh*512 + i0 + row)*512;
    float v[8];
    float m = -1e30f;
    #pragma unroll
    for (int r = 0; r < 8; ++r) {
      v[r] = Ssm[row][lane + 64*r]*0.125f + bf2f(Srow[lane + 64*r]);
      m = fmaxf(m, v[r]);
    }
    #pragma unroll
    for (int o = 32; o > 0; o >>= 1) m = fmaxf(m, __shfl_xor(m, o, 64));
    float s = 0.f;
    #pragma unroll
    for (int r = 0; r < 8; ++r) { v[r] = __expf(v[r] - m); s += v[r]; }
    #pragma unroll
    for (int o = 32; o > 0; o >>= 1) s += __shfl_xor(s, o, 64);
    const float inv = 1.f / s;
    #pragma unroll
    for (int r = 0; r < 8; ++r) Pt[(lane + 64*r)*20 + row] = v[r] * inv;
  }
  __syncthreads();

  // ---- Phase C: PV (fp32) ----
  {
    const int d = lane, ig = w;
    const float* V = src + (size_t)b*512*512 + h*64 + d;
    float acc0=0.f, acc1=0.f, acc2=0.f, acc3=0.f;
    #pragma unroll 8
    for (int j = 0; j < 512; ++j) {
      const float vv = V[(size_t)j*512];
      const float4 p = *(const float4*)&Pt[j*20 + ig*4];
      acc0 = fmaf(p.x, vv, acc0); acc1 = fmaf(p.y, vv, acc1);
      acc2 = fmaf(p.z, vv, acc2); acc3 = fmaf(p.w, vv, acc3);
    }
    float* out = attn_out + ((size_t)(b*512) + i0)*512 + h*64 + d;
    out[(size_t)(ig*4+0)*512] = acc0;
    out[(size_t)(ig*4+1)*512] = acc1;
    out[(size_t)(ig*4+2)*512] = acc2;
    out[(size_t)(ig*4+3)*512] = acc3;
  }
}

// ---------------------------------------------------------------------------
// K3: x = LN(src + attn_out) * g1 + be1 ; also emit x in bf16
// ---------------------------------------------------------------------------
__global__ __launch_bounds__(256) void ln1_kernel(
    const float* __restrict__ a, const float* __restrict__ bb,
    const float* __restrict__ g, const float* __restrict__ be,
    float* __restrict__ out, ushort_t* __restrict__ xb)
{
  const int bi = blockIdx.x, tid = threadIdx.x;
  const int d0 = tid * 2;
  const float2 xa = *(const float2*)&a [bi*512 + d0];
  const float2 xv = *(const float2*)&bb[bi*512 + d0];
  const float y0 = xa.x + xv.x;
  const float y1 = xa.y + xv.y;
  float s1 = y0 + y1, s2 = y0*y0 + y1*y1;
  #pragma unroll
  for (int o = 32; o > 0; o >>= 1) { s1 += __shfl_xor(s1, o, 64); s2 += __shfl_xor(s2, o, 64); }
  __shared__ float r1[4], r2[4];
  const int w = tid >> 6;
  if ((tid & 63) == 0) { r1[w] = s1; r2[w] = s2; }
  __syncthreads();
  const float t1 = r1[0] + r1[1] + r1[2] + r1[3];
  const float t2 = r2[0] + r2[1] + r2[2] + r2[3];
  const float mu  = t1 * (1.f/512.f);
  const float var = t2 * (1.f/512.f) - mu*mu;
  const float rs  = rsqrtf(var + LN_EPS);
  const float2 gg = *(const float2*)&g [d0];
  const float2 bv = *(const float2*)&be[d0];
  const float o0 = (y0 - mu)*rs*gg.x + bv.x;
  const float o1 = (y1 - mu)*rs*gg.y + bv.y;
  out[bi*512 + d0]     = o0;
  out[bi*512 + d0 + 1] = o1;
  *(uint_t*)&xb[bi*512 + d0] = (uint_t)f2bf(o0) | ((uint_t)f2bf(o1) << 16);
}

// ---------------------------------------------------------------------------
// K4: MFMA GEMM  ff = leaky_relu(xb @ w1b^T + b1), bf16 out
// BM=128 BN=64 BK=64; 4 waves 2x2; wave tile 64x32 (4x2 frags); grid (8,32)
// ---------------------------------------------------------------------------
__global__ __launch_bounds__(256) void gemm_ffn1(
    const ushort_t* __restrict__ A,   // [1024][512] bf16 bits
    const ushort_t* __restrict__ B,   // [2048][512] bf16 bits
    const float* __restrict__ bias, ushort_t* __restrict__ C)  // [1024][2048]
{
  __shared__ ushort_t Asm[128*64];
  __shared__ ushort_t Bsm[64*64];
  const int tid = threadIdx.x;
  const int m0 = blockIdx.x * 128, n0 = blockIdx.y * 64;
  const int lane = tid & 63;
  const int wr = (tid >> 7) & 1, wc = (tid >> 6) & 1;

  const int arow = tid >> 1, ar7 = arow & 7;
  const int acb  = (tid & 1) * 4;
  const int brow = tid >> 2, br7 = brow & 7;
  const int bcb  = (tid & 3) * 2;

  f32x4 acc[4][2] = {};
  for (int kt = 0; kt < 8; ++kt) {
    const uint4* ga = (const uint4*)(A + (size_t)(m0 + arow)*512 + kt*64);
    const uint4 av0 = ga[acb+0], av1 = ga[acb+1], av2 = ga[acb+2], av3 = ga[acb+3];
    const uint4* gb = (const uint4*)(B + (size_t)(n0 + brow)*512 + kt*64);
    const uint4 bv0 = gb[bcb+0], bv1 = gb[bcb+1];
    __syncthreads();
    *(uint4*)&Asm[arow*64 + (((acb+0) ^ ar7) << 3)] = av0;
    *(uint4*)&Asm[arow*64 + (((acb+1) ^ ar7) << 3)] = av1;
    *(uint4*)&Asm[arow*64 + (((acb+2) ^ ar7) << 3)] = av2;
    *(uint4*)&Asm[arow*64 + (((acb+3) ^ ar7) << 3)] = av3;
    *(uint4*)&Bsm[brow*64 + (((bcb+0) ^ br7) << 3)] = bv0;
    *(uint4*)&Bsm[brow*64 + (((bcb+1) ^ br7) << 3)] = bv1;
    __syncthreads();
    #pragma unroll
    for (int kk = 0; kk < 2; ++kk) {
      bf16x8 af[4], bfm[2];
      #pragma unroll
      for (int fm = 0; fm < 4; ++fm) {
        const int r = wr*64 + fm*16 + (lane & 15);
        const int c = (kk*4 + (lane >> 4)) ^ (r & 7);
        af[fm] = *(const bf16x8*)&Asm[r*64 + c*8];
      }
      #pragma unroll
      for (int fn = 0; fn < 2; ++fn) {
        const int r = wc*32 + fn*16 + (lane & 15);
        const int c = (kk*4 + (lane >> 4)) ^ (r & 7);
        bfm[fn] = *(const bf16x8*)&Bsm[r*64 + c*8];
      }
      #pragma unroll
      for (int fm = 0; fm < 4; ++fm)
        #pragma unroll
        for (int fn = 0; fn < 2; ++fn)
          acc[fm][fn] = __builtin_amdgcn_mfma_f32_16x16x32_bf16(af[fm], bfm[fn], acc[fm][fn], 0, 0, 0);
    }
  }
  #pragma unroll
  for (int fn = 0; fn < 2; ++fn) {
    const int col = n0 + wc*32 + fn*16 + (lane & 15);
    const float bb = bias[col];
    #pragma unroll
    for (int fm = 0; fm < 4; ++fm) {
      #pragma unroll
      for (int r = 0; r < 4; ++r) {
        const int row = m0 + wr*64 + fm*16 + (lane >> 4)*4 + r;
        float t = acc[fm][fn][r] + bb;
        t = t > 0.f ? t : 0.01f*t;
        C[(size_t)row*2048 + col] = f2bf(t);
      }
    }
  }
}

// ---------------------------------------------------------------------------
// K5: MFMA GEMM  p[z] = ff @ w2b^T over K-slice z*512..+512, fp32 partials
// grid (8, 8, 4)
// ---------------------------------------------------------------------------
__global__ __launch_bounds__(256) void gemm_ffn2(
    const ushort_t* __restrict__ A,   // ff [1024][2048] bf16 bits
    const ushort_t* __restrict__ B,   // w2b [512][2048] bf16 bits
    float* __restrict__ P)            // [4][1024][512]
{
  __shared__ ushort_t Asm[128*64];
  __shared__ ushort_t Bsm[64*64];
  const int tid = threadIdx.x;
  const int m0 = blockIdx.x * 128, n0 = blockIdx.y * 64;
  const int kbase = blockIdx.z * 512;
  float* outp = P + (size_t)blockIdx.z * 524288;
  const int lane = tid & 63;
  const int wr = (tid >> 7) & 1, wc = (tid >> 6) & 1;

  const int arow = tid >> 1, ar7 = arow & 7;
  const int acb  = (tid & 1) * 4;
  const int brow = tid >> 2, br7 = brow & 7;
  const int bcb  = (tid & 3) * 2;

  f32x4 acc[4][2] = {};
  for (int kt = 0; kt < 8; ++kt) {
    const uint4* ga = (const uint4*)(A + (size_t)(m0 + arow)*2048 + kbase + kt*64);
    const uint4 av0 = ga[acb+0], av1 = ga[acb+1], av2 = ga[acb+2], av3 = ga[acb+3];
    const uint4* gb = (const uint4*)(B + (size_t)(n0 + brow)*2048 + kbase + kt*64);
    const uint4 bv0 = gb[bcb+0], bv1 = gb[bcb+1];
    __syncthreads();
    *(uint4*)&Asm[arow*64 + (((acb+0) ^ ar7) << 3)] = av0;
    *(uint4*)&Asm[arow*64 + (((acb+1) ^ ar7) << 3)] = av1;
    *(uint4*)&Asm[arow*64 + (((acb+2) ^ ar7) << 3)] = av2;
    *(uint4*)&Asm[arow*64 + (((acb+3) ^ ar7) << 3)] = av3;
    *(uint4*)&Bsm[brow*64 + (((bcb+0) ^ br7) << 3)] = bv0;
    *(uint4*)&Bsm[brow*64 + (((bcb+1) ^ br7) << 3)] = bv1;
    __syncthreads();
    #pragma unroll
    for (int kk = 0; kk < 2; ++kk) {
      bf16x8 af[4], bfm[2];
      #pragma unroll
      for (int fm = 0; fm < 4; ++fm) {
        const int r = wr*64 + fm*16 + (lane & 15);
        const int c = (kk*4 + (lane >> 4)) ^ (r & 7);
        af[fm] = *(const bf16x8*)&Asm[r*64 + c*8];
      }
      #pragma unroll
      for (int fn = 0; fn < 2; ++fn) {
        const int r = wc*32 + fn*16 + (lane & 15);
        const int c = (kk*4 + (lane >> 4)) ^ (r & 7);
        bfm[fn] = *(const bf16x8*)&Bsm[r*64 + c*8];
      }
      #pragma unroll
      for (int fm = 0; fm < 4; ++fm)
        #pragma unroll
        for (int fn = 0; fn < 2; ++fn)
          acc[fm][fn] = __builtin_amdgcn_mfma_f32_16x16x32_bf16(af[fm], bfm[fn], acc[fm][fn], 0, 0, 0);
    }
  }
  #pragma unroll
  for (int fn = 0; fn < 2; ++fn) {
    const int col = n0 + wc*32 + fn*16 + (lane & 15);
    #pragma unroll
    for (int fm = 0; fm < 4; ++fm) {
      #pragma unroll
      for (int r = 0; r < 4; ++r) {
        const int row = m0 + wr*64 + fm*16 + (lane >> 4)*4 + r;
        outp[(size_t)row*512 + col] = acc[fm][fn][r];
      }
    }
  }
}

// ---------------------------------------------------------------------------
// K6: out = LN(x + p0+p1+p2+p3 + b2) * g2 + be2
// ---------------------------------------------------------------------------
__global__ __launch_bounds__(256) void ln2_kernel(
    const float* __restrict__ p, const float* __restrict__ x,
    const float* __restrict__ b2, const float* __restrict__ g2,
    const float* __restrict__ be2, float* __restrict__ out)
{
  const int bi = blockIdx.x, tid = threadIdx.x;
  const int d0 = tid * 2;
  const float2 a0 = *(const float2*)&p[bi*512 + d0];
  const float2 a1 = *(const float2*)&p[524288 + bi*512 + d0];
  const float2 a2 = *(const float2*)&p[1048576 + bi*512 + d0];
  const float2 a3 = *(const float2*)&p[1572864 + bi*512 + d0];
  const float2 xr = *(const float2*)&x [bi*512 + d0];
  const float2 bb = *(const float2*)&b2[d0];
  const float y0 = a0.x + a1.x + a2.x + a3.x + bb.x + xr.x;
  const float y1 = a0.y + a1.y + a2.y + a3.y + bb.y + xr.y;
  float s1 = y0 + y1, s2 = y0*y0 + y1*y1;
  #pragma unroll
  for (int o = 32; o > 0; o >>= 1) { s1 += __shfl_xor(s1, o, 64); s2 += __shfl_xor(s2, o, 64); }
  __shared__ float r1[4], r2[4];
  const int w = tid >> 6;
  if ((tid & 63) == 0) { r1[w] = s1; r2[w] = s2; }
  __syncthreads();
  const float t1 = r1[0] + r1[1] + r1[2] + r1[3];
  const float t2 = r2[0] + r2[1] + r2[2] + r2[3];
  const float mu  = t1 * (1.f/512.f);
  const float var = t2 * (1.f/512.f) - mu*mu;
  const float rs  = rsqrtf(var + LN_EPS);
  const float2 g  = *(const float2*)&g2 [d0];
  const float2 be = *(const float2*)&be2[d0];
  out[bi*512 + d0]     = (y0 - mu)*rs*g.x + be.x;
  out[bi*512 + d0 + 1] = (y1 - mu)*rs*g.y + be.y;
}

// ---------------------------------------------------------------------------
extern "C" void kernel_launch(void* const* d_in, const int* in_sizes, int n_in,
                              void* d_out, int out_size, void* d_ws, size_t ws_size,
                              hipStream_t stream) {
  const float* src  = (const float*)d_in[0];
  const float* relf = (const float*)d_in[1];
  const float* rel_w = (const float*)d_in[2];
  const float* rel_b = (const float*)d_in[3];
  const float* w1 = (const float*)d_in[4];
  const float* b1 = (const float*)d_in[5];
  const float* w2 = (const float*)d_in[6];
  const float* b2 = (const float*)d_in[7];
  const float* g1  = (const float*)d_in[8];
  const float* be1 = (const float*)d_in[9];
  const float* g2  = (const float*)d_in[10];
  const float* be2 = (const float*)d_in[11];
  float* out = (float*)d_out;

  float* ws = (float*)d_ws;
  ushort_t* srcb = (ushort_t*)(ws);                 // 524288 bf16 -> 262144 f
  ushort_t* Sb   = (ushort_t*)(ws + 262144);        // 4194304 bf16 -> 2097152 f
  float*    attn = ws + 2359296;                    // 524288 f
  float*    x    = ws + 2883584;                    // 524288 f
  ushort_t* xb   = (ushort_t*)(ws + 3407872);       // 262144 f
  ushort_t* w1b  = (ushort_t*)(ws + 3670016);       // 524288 f
  ushort_t* w2b  = (ushort_t*)(ws + 4194304);       // 524288 f
  ushort_t* ffb  = (ushort_t*)(ws + 4718592);       // 1048576 f
  float*    p    = ws + 5767168;                    // 2097152 f

  rel_plus_kernel  <<<1088, 256, 0, stream>>>(src, rel_w, rel_b, relf, w1, w2,
                                              srcb, w1b, w2b, Sb);
  softmax_pv_kernel<<<dim3(16, 32), 256, 0, stream>>>(Sb, srcb, src, attn);
  ln1_kernel       <<<1024, 256, 0, stream>>>(src, attn, g1, be1, x, xb);
  gemm_ffn1        <<<dim3(8, 32), 256, 0, stream>>>(xb, w1b, b1, ffb);
  gemm_ffn2        <<<dim3(8, 8, 4), 256, 0, stream>>>(ffb, w2b, p);
  ln2_kernel       <<<1024, 256, 0, stream>>>(p, x, b2, g2, be2, out);
}

// Round 6
// 96.237 us; speedup vs baseline: 3.6795x; 1.0275x over previous
//
#include <hip/hip_runtime.h>
#include <math.h>

#define LN_EPS 1e-5f
// B=2 L=512 D=512 H=8 DH=64 C=64 F=2048
// Sb layout (bf16): Sb[b,h,i,j] = Sb[((b*8+h)*512 + i)*512 + j]

typedef __bf16 bf16x8 __attribute__((ext_vector_type(8)));
typedef unsigned short u16x8 __attribute__((ext_vector_type(8)));
typedef float f32x4 __attribute__((ext_vector_type(4)));
typedef unsigned short ushort_t;
typedef unsigned int uint_t;

__device__ inline ushort_t f2bf(float f) {
  uint_t u = __float_as_uint(f);
  return (ushort_t)((u + 0x7FFFu + ((u >> 16) & 1u)) >> 16);
}
__device__ inline float bf2f(ushort_t b) {
  return __uint_as_float(((uint_t)b) << 16);
}
__device__ inline bf16x8 cvt8(float4 a, float4 b) {
  u16x8 u;
  u[0]=f2bf(a.x); u[1]=f2bf(a.y); u[2]=f2bf(a.z); u[3]=f2bf(a.w);
  u[4]=f2bf(b.x); u[5]=f2bf(b.y); u[6]=f2bf(b.z); u[7]=f2bf(b.w);
  return __builtin_bit_cast(bf16x8, u);
}

// ---------------------------------------------------------------------------
// K1 "qw_conv": blocks 0..1023: qwb[b,i,h,c] (bf16) + qb[b,i,h].
// blocks 1024..1087: convert src->srcb, w1->w1b, w2->w2b.
// ---------------------------------------------------------------------------
__global__ __launch_bounds__(256) void qw_conv_kernel(
    const float* __restrict__ src, const float* __restrict__ rel_w,
    const float* __restrict__ rel_b,
    const float* __restrict__ w1, const float* __restrict__ w2,
    ushort_t* __restrict__ qwb, float* __restrict__ qb,
    ushort_t* __restrict__ srcb, ushort_t* __restrict__ w1b,
    ushort_t* __restrict__ w2b)
{
  const int tid = threadIdx.x;
  if (blockIdx.x >= 1024) {
    const int cb = blockIdx.x - 1024;          // 0..63
    const int tg = cb*256 + tid;               // 0..16383
    for (int it = tg; it < 65536; it += 16384) {
      const int i = it*8;
      const float4 a = *(const float4*)(src + i);
      const float4 b = *(const float4*)(src + i + 4);
      uint4 v;
      v.x = (uint_t)f2bf(a.x) | ((uint_t)f2bf(a.y) << 16);
      v.y = (uint_t)f2bf(a.z) | ((uint_t)f2bf(a.w) << 16);
      v.z = (uint_t)f2bf(b.x) | ((uint_t)f2bf(b.y) << 16);
      v.w = (uint_t)f2bf(b.z) | ((uint_t)f2bf(b.w) << 16);
      *(uint4*)(srcb + i) = v;
    }
    for (int it = tg; it < 131072; it += 16384) {
      const int i = it*8;
      const float4 a = *(const float4*)(w1 + i);
      const float4 b = *(const float4*)(w1 + i + 4);
      uint4 v;
      v.x = (uint_t)f2bf(a.x) | ((uint_t)f2bf(a.y) << 16);
      v.y = (uint_t)f2bf(a.z) | ((uint_t)f2bf(a.w) << 16);
      v.z = (uint_t)f2bf(b.x) | ((uint_t)f2bf(b.y) << 16);
      v.w = (uint_t)f2bf(b.z) | ((uint_t)f2bf(b.w) << 16);
      *(uint4*)(w1b + i) = v;
    }
    for (int it = tg; it < 131072; it += 16384) {
      const int i = it*8;
      const float4 a = *(const float4*)(w2 + i);
      const float4 b = *(const float4*)(w2 + i + 4);
      uint4 v;
      v.x = (uint_t)f2bf(a.x) | ((uint_t)f2bf(a.y) << 16);
      v.y = (uint_t)f2bf(a.z) | ((uint_t)f2bf(a.w) << 16);
      v.z = (uint_t)f2bf(b.x) | ((uint_t)f2bf(b.y) << 16);
      v.w = (uint_t)f2bf(b.z) | ((uint_t)f2bf(b.w) << 16);
      *(uint4*)(w2b + i) = v;
    }
    return;
  }

  const int bi = blockIdx.x;     // b*512 + i
  __shared__ float q_sh[512];
  q_sh[tid]       = src[bi*512 + tid];
  q_sh[tid + 256] = src[bi*512 + tid + 256];
  __syncthreads();
  for (int idx = tid; idx < 512; idx += 256) {
    const int h = idx >> 6, c = idx & 63;
    float s = 0.f;
    #pragma unroll 8
    for (int d = 0; d < 64; ++d)
      s = fmaf(q_sh[h*64+d], rel_w[(h*64+d)*64 + c], s);
    qwb[(size_t)bi*512 + idx] = f2bf(s);
  }
  if (tid < 8) {
    float s = 0.f;
    for (int d = 0; d < 64; ++d) s = fmaf(q_sh[tid*64+d], rel_b[tid*64+d], s);
    qb[bi*8 + tid] = s;
  }
}

// ---------------------------------------------------------------------------
// K2 "rel_stream": pure 134MB stream:
//   Sb[b,h,i,j] = bf16( sum_c RF[b,i,j,c]*qw[h,c] + qb[h] ) via MFMA.
// ---------------------------------------------------------------------------
__global__ __launch_bounds__(256) void rel_stream_kernel(
    const float* __restrict__ relf, const ushort_t* __restrict__ qwb,
    const float* __restrict__ qb, ushort_t* __restrict__ Sb)
{
  const int bi = blockIdx.x;           // b*512 + i
  const int b = bi >> 9, i = bi & 511;
  const int tid = threadIdx.x;
  const int lane = tid & 63, w = tid >> 6;
  const int hl = lane & 15;          // D col (head), valid < 8
  const int kc = lane >> 4;          // k-chunk 0..3
  const int h  = hl & 7;

  const bf16x8 b0 = *(const bf16x8*)&qwb[(size_t)bi*512 + h*64 + kc*8];
  const bf16x8 b1 = *(const bf16x8*)&qwb[(size_t)bi*512 + h*64 + 32 + kc*8];
  const float qbv = qb[bi*8 + h];
  ushort_t* Sp = Sb + ((size_t)(b*8+h)*512 + i)*512;

  #pragma unroll
  for (int t = 0; t < 8; ++t) {
    const int j0 = (t*4 + w)*16;
    const int j  = j0 + hl;                  // A row
    const float* rf = relf + ((size_t)bi*512 + j)*64 + kc*8;
    const float4 x0 = *(const float4*)rf;
    const float4 x1 = *(const float4*)(rf + 4);
    const float4 y0 = *(const float4*)(rf + 32);
    const float4 y1 = *(const float4*)(rf + 36);
    const bf16x8 a0 = cvt8(x0, x1);
    const bf16x8 a1 = cvt8(y0, y1);
    f32x4 acc = {0.f, 0.f, 0.f, 0.f};
    acc = __builtin_amdgcn_mfma_f32_16x16x32_bf16(a0, b0, acc, 0, 0, 0);
    acc = __builtin_amdgcn_mfma_f32_16x16x32_bf16(a1, b1, acc, 0, 0, 0);
    if (hl < 8) {
      const float v0 = acc[0] + qbv, v1 = acc[1] + qbv;
      const float v2 = acc[2] + qbv, v3 = acc[3] + qbv;
      uint2 pk;
      pk.x = (uint_t)f2bf(v0) | ((uint_t)f2bf(v1) << 16);
      pk.y = (uint_t)f2bf(v2) | ((uint_t)f2bf(v3) << 16);
      *(uint2*)&Sp[j0 + kc*4] = pk;
    }
  }
}

// ---------------------------------------------------------------------------
// K3: per (bh, it=16 rows): base scores (MFMA) -> LDS;
//     softmax( 0.125*base + Sb ) -> Pt; PV (fp32) -> attn_out
// ---------------------------------------------------------------------------
__global__ __launch_bounds__(256) void softmax_pv_kernel(
    const ushort_t* __restrict__ Sb, const ushort_t* __restrict__ srcb,
    const float* __restrict__ src, float* __restrict__ attn_out)
{
  const int bh = blockIdx.x, it = blockIdx.y;
  const int b = bh >> 3, h = bh & 7;
  const int i0 = it * 16;
  const int tid = threadIdx.x;
  const int lane = tid & 63, w = tid >> 6;
  __shared__ float Ssm[16][516];
  __shared__ float Pt[512*20];

  // ---- Phase A: base scores Q.K^T via MFMA ----
  {
    const int il = lane & 15, kc = lane >> 4;
    const bf16x8 aq0 = *(const bf16x8*)&srcb[(size_t)(b*512 + i0 + il)*512 + h*64 + kc*8];
    const bf16x8 aq1 = *(const bf16x8*)&srcb[(size_t)(b*512 + i0 + il)*512 + h*64 + 32 + kc*8];
    #pragma unroll
    for (int t = 0; t < 8; ++t) {
      const int jt = t*4 + w;
      const int j  = jt*16 + il;             // B col
      const bf16x8 bk0 = *(const bf16x8*)&srcb[(size_t)(b*512 + j)*512 + h*64 + kc*8];
      const bf16x8 bk1 = *(const bf16x8*)&srcb[(size_t)(b*512 + j)*512 + h*64 + 32 + kc*8];
      f32x4 acc = {0.f, 0.f, 0.f, 0.f};
      acc = __builtin_amdgcn_mfma_f32_16x16x32_bf16(aq0, bk0, acc, 0, 0, 0);
      acc = __builtin_amdgcn_mfma_f32_16x16x32_bf16(aq1, bk1, acc, 0, 0, 0);
      #pragma unroll
      for (int r = 0; r < 4; ++r) Ssm[kc*4 + r][jt*16 + il] = acc[r];
    }
  }
  __syncthreads();

  // ---- Phase B: softmax rows ----
  #pragma unroll
  for (int k = 0; k < 4; ++k) {
    const int row = w*4 + k;
    const ushort_t* Srow = Sb + ((size_t)bh*512 + i0 + row)*512;
    float v[8];
    float m = -1e30f;
    #pragma unroll
    for (int r = 0; r < 8; ++r) {
      v[r] = Ssm[row][lane + 64*r]*0.125f + bf2f(Srow[lane + 64*r]);
      m = fmaxf(m, v[r]);
    }
    #pragma unroll
    for (int o = 32; o > 0; o >>= 1) m = fmaxf(m, __shfl_xor(m, o, 64));
    float s = 0.f;
    #pragma unroll
    for (int r = 0; r < 8; ++r) { v[r] = __expf(v[r] - m); s += v[r]; }
    #pragma unroll
    for (int o = 32; o > 0; o >>= 1) s += __shfl_xor(s, o, 64);
    const float inv = 1.f / s;
    #pragma unroll
    for (int r = 0; r < 8; ++r) Pt[(lane + 64*r)*20 + row] = v[r] * inv;
  }
  __syncthreads();

  // ---- Phase C: PV (fp32) ----
  {
    const int d = lane, ig = w;
    const float* V = src + (size_t)b*512*512 + h*64 + d;
    float acc0=0.f, acc1=0.f, acc2=0.f, acc3=0.f;
    #pragma unroll 8
    for (int j = 0; j < 512; ++j) {
      const float vv = V[(size_t)j*512];
      const float4 p = *(const float4*)&Pt[j*20 + ig*4];
      acc0 = fmaf(p.x, vv, acc0); acc1 = fmaf(p.y, vv, acc1);
      acc2 = fmaf(p.z, vv, acc2); acc3 = fmaf(p.w, vv, acc3);
    }
    float* out = attn_out + ((size_t)(b*512) + i0)*512 + h*64 + d;
    out[(size_t)(ig*4+0)*512] = acc0;
    out[(size_t)(ig*4+1)*512] = acc1;
    out[(size_t)(ig*4+2)*512] = acc2;
    out[(size_t)(ig*4+3)*512] = acc3;
  }
}

// ---------------------------------------------------------------------------
// K4: x = LN(src + attn_out) * g1 + be1 ; also emit x in bf16
// ---------------------------------------------------------------------------
__global__ __launch_bounds__(256) void ln1_kernel(
    const float* __restrict__ a, const float* __restrict__ bb,
    const float* __restrict__ g, const float* __restrict__ be,
    float* __restrict__ out, ushort_t* __restrict__ xb)
{
  const int bi = blockIdx.x, tid = threadIdx.x;
  const int d0 = tid * 2;
  const float2 xa = *(const float2*)&a [bi*512 + d0];
  const float2 xv = *(const float2*)&bb[bi*512 + d0];
  const float y0 = xa.x + xv.x;
  const float y1 = xa.y + xv.y;
  float s1 = y0 + y1, s2 = y0*y0 + y1*y1;
  #pragma unroll
  for (int o = 32; o > 0; o >>= 1) { s1 += __shfl_xor(s1, o, 64); s2 += __shfl_xor(s2, o, 64); }
  __shared__ float r1[4], r2[4];
  const int w = tid >> 6;
  if ((tid & 63) == 0) { r1[w] = s1; r2[w] = s2; }
  __syncthreads();
  const float t1 = r1[0] + r1[1] + r1[2] + r1[3];
  const float t2 = r2[0] + r2[1] + r2[2] + r2[3];
  const float mu  = t1 * (1.f/512.f);
  const float var = t2 * (1.f/512.f) - mu*mu;
  const float rs  = rsqrtf(var + LN_EPS);
  const float2 gg = *(const float2*)&g [d0];
  const float2 bv = *(const float2*)&be[d0];
  const float o0 = (y0 - mu)*rs*gg.x + bv.x;
  const float o1 = (y1 - mu)*rs*gg.y + bv.y;
  out[bi*512 + d0]     = o0;
  out[bi*512 + d0 + 1] = o1;
  *(uint_t*)&xb[bi*512 + d0] = (uint_t)f2bf(o0) | ((uint_t)f2bf(o1) << 16);
}

// ---------------------------------------------------------------------------
// K5: MFMA GEMM  ff = leaky_relu(xb @ w1b^T + b1), bf16 out
// BM=64 BN=64 BK=64; 4 waves 2x2, wave tile 32x32 (2x2 frags); grid (16,32)
// ---------------------------------------------------------------------------
__global__ __launch_bounds__(256) void gemm_ffn1(
    const ushort_t* __restrict__ A,   // [1024][512]
    const ushort_t* __restrict__ B,   // [2048][512]
    const float* __restrict__ bias, ushort_t* __restrict__ C)  // [1024][2048]
{
  __shared__ ushort_t Asm[64*64];
  __shared__ ushort_t Bsm[64*64];
  const int tid = threadIdx.x;
  const int m0 = blockIdx.x * 64, n0 = blockIdx.y * 64;
  const int lane = tid & 63;
  const int wr = (tid >> 7) & 1, wc = (tid >> 6) & 1;

  const int row = tid >> 2, r7 = row & 7;
  const int cb  = (tid & 3) * 2;

  f32x4 acc[2][2] = {};
  for (int kt = 0; kt < 8; ++kt) {
    const uint4* ga = (const uint4*)(A + (size_t)(m0 + row)*512 + kt*64);
    const uint4 av0 = ga[cb], av1 = ga[cb+1];
    const uint4* gb = (const uint4*)(B + (size_t)(n0 + row)*512 + kt*64);
    const uint4 bv0 = gb[cb], bv1 = gb[cb+1];
    __syncthreads();
    *(uint4*)&Asm[row*64 + (((cb+0) ^ r7) << 3)] = av0;
    *(uint4*)&Asm[row*64 + (((cb+1) ^ r7) << 3)] = av1;
    *(uint4*)&Bsm[row*64 + (((cb+0) ^ r7) << 3)] = bv0;
    *(uint4*)&Bsm[row*64 + (((cb+1) ^ r7) << 3)] = bv1;
    __syncthreads();
    #pragma unroll
    for (int kk = 0; kk < 2; ++kk) {
      bf16x8 af[2], bfm[2];
      #pragma unroll
      for (int fm = 0; fm < 2; ++fm) {
        const int r = wr*32 + fm*16 + (lane & 15);
        const int c = (kk*4 + (lane >> 4)) ^ (r & 7);
        af[fm] = *(const bf16x8*)&Asm[r*64 + c*8];
      }
      #pragma unroll
      for (int fn = 0; fn < 2; ++fn) {
        const int r = wc*32 + fn*16 + (lane & 15);
        const int c = (kk*4 + (lane >> 4)) ^ (r & 7);
        bfm[fn] = *(const bf16x8*)&Bsm[r*64 + c*8];
      }
      #pragma unroll
      for (int fm = 0; fm < 2; ++fm)
        #pragma unroll
        for (int fn = 0; fn < 2; ++fn)
          acc[fm][fn] = __builtin_amdgcn_mfma_f32_16x16x32_bf16(af[fm], bfm[fn], acc[fm][fn], 0, 0, 0);
    }
  }
  #pragma unroll
  for (int fn = 0; fn < 2; ++fn) {
    const int col = n0 + wc*32 + fn*16 + (lane & 15);
    const float bb = bias[col];
    #pragma unroll
    for (int fm = 0; fm < 2; ++fm) {
      #pragma unroll
      for (int r = 0; r < 4; ++r) {
        const int orow = m0 + wr*32 + fm*16 + (lane >> 4)*4 + r;
        float t = acc[fm][fn][r] + bb;
        t = t > 0.f ? t : 0.01f*t;
        C[(size_t)orow*2048 + col] = f2bf(t);
      }
    }
  }
}

// ---------------------------------------------------------------------------
// K6: MFMA GEMM  p[z] = ff @ w2b^T over K-slice z*512..+512, fp32 partials
// BM=64 BN=64; grid (16, 8, 4)
// ---------------------------------------------------------------------------
__global__ __launch_bounds__(256) void gemm_ffn2(
    const ushort_t* __restrict__ A,   // ff [1024][2048]
    const ushort_t* __restrict__ B,   // w2b [512][2048]
    float* __restrict__ P)            // [4][1024][512]
{
  __shared__ ushort_t Asm[64*64];
  __shared__ ushort_t Bsm[64*64];
  const int tid = threadIdx.x;
  const int m0 = blockIdx.x * 64, n0 = blockIdx.y * 64;
  const int kbase = blockIdx.z * 512;
  float* outp = P + (size_t)blockIdx.z * 524288;
  const int lane = tid & 63;
  const int wr = (tid >> 7) & 1, wc = (tid >> 6) & 1;

  const int row = tid >> 2, r7 = row & 7;
  const int cb  = (tid & 3) * 2;

  f32x4 acc[2][2] = {};
  for (int kt = 0; kt < 8; ++kt) {
    const uint4* ga = (const uint4*)(A + (size_t)(m0 + row)*2048 + kbase + kt*64);
    const uint4 av0 = ga[cb], av1 = ga[cb+1];
    const uint4* gb = (const uint4*)(B + (size_t)(n0 + row)*2048 + kbase + kt*64);
    const uint4 bv0 = gb[cb], bv1 = gb[cb+1];
    __syncthreads();
    *(uint4*)&Asm[row*64 + (((cb+0) ^ r7) << 3)] = av0;
    *(uint4*)&Asm[row*64 + (((cb+1) ^ r7) << 3)] = av1;
    *(uint4*)&Bsm[row*64 + (((cb+0) ^ r7) << 3)] = bv0;
    *(uint4*)&Bsm[row*64 + (((cb+1) ^ r7) << 3)] = bv1;
    __syncthreads();
    #pragma unroll
    for (int kk = 0; kk < 2; ++kk) {
      bf16x8 af[2], bfm[2];
      #pragma unroll
      for (int fm = 0; fm < 2; ++fm) {
        const int r = wr*32 + fm*16 + (lane & 15);
        const int c = (kk*4 + (lane >> 4)) ^ (r & 7);
        af[fm] = *(const bf16x8*)&Asm[r*64 + c*8];
      }
      #pragma unroll
      for (int fn = 0; fn < 2; ++fn) {
        const int r = wc*32 + fn*16 + (lane & 15);
        const int c = (kk*4 + (lane >> 4)) ^ (r & 7);
        bfm[fn] = *(const bf16x8*)&Bsm[r*64 + c*8];
      }
      #pragma unroll
      for (int fm = 0; fm < 2; ++fm)
        #pragma unroll
        for (int fn = 0; fn < 2; ++fn)
          acc[fm][fn] = __builtin_amdgcn_mfma_f32_16x16x32_bf16(af[fm], bfm[fn], acc[fm][fn], 0, 0, 0);
    }
  }
  #pragma unroll
  for (int fn = 0; fn < 2; ++fn) {
    const int col = n0 + wc*32 + fn*16 + (lane & 15);
    #pragma unroll
    for (int fm = 0; fm < 2; ++fm) {
      #pragma unroll
      for (int r = 0; r < 4; ++r) {
        const int orow = m0 + wr*32 + fm*16 + (lane >> 4)*4 + r;
        outp[(size_t)orow*512 + col] = acc[fm][fn][r];
      }
    }
  }
}

// ---------------------------------------------------------------------------
// K7: out = LN(x + p0+p1+p2+p3 + b2) * g2 + be2
// ---------------------------------------------------------------------------
__global__ __launch_bounds__(256) void ln2_kernel(
    const float* __restrict__ p, const float* __restrict__ x,
    const float* __restrict__ b2, const float* __restrict__ g2,
    const float* __restrict__ be2, float* __restrict__ out)
{
  const int bi = blockIdx.x, tid = threadIdx.x;
  const int d0 = tid * 2;
  const float2 a0 = *(const float2*)&p[bi*512 + d0];
  const float2 a1 = *(const float2*)&p[524288 + bi*512 + d0];
  const float2 a2 = *(const float2*)&p[1048576 + bi*512 + d0];
  const float2 a3 = *(const float2*)&p[1572864 + bi*512 + d0];
  const float2 xr = *(const float2*)&x [bi*512 + d0];
  const float2 bb = *(const float2*)&b2[d0];
  const float y0 = a0.x + a1.x + a2.x + a3.x + bb.x + xr.x;
  const float y1 = a0.y + a1.y + a2.y + a3.y + bb.y + xr.y;
  float s1 = y0 + y1, s2 = y0*y0 + y1*y1;
  #pragma unroll
  for (int o = 32; o > 0; o >>= 1) { s1 += __shfl_xor(s1, o, 64); s2 += __shfl_xor(s2, o, 64); }
  __shared__ float r1[4], r2[4];
  const int w = tid >> 6;
  if ((tid & 63) == 0) { r1[w] = s1; r2[w] = s2; }
  __syncthreads();
  const float t1 = r1[0] + r1[1] + r1[2] + r1[3];
  const float t2 = r2[0] + r2[1] + r2[2] + r2[3];
  const float mu  = t1 * (1.f/512.f);
  const float var = t2 * (1.f/512.f) - mu*mu;
  const float rs  = rsqrtf(var + LN_EPS);
  const float2 g  = *(const float2*)&g2 [d0];
  const float2 be = *(const float2*)&be2[d0];
  out[bi*512 + d0]     = (y0 - mu)*rs*g.x + be.x;
  out[bi*512 + d0 + 1] = (y1 - mu)*rs*g.y + be.y;
}

// ---------------------------------------------------------------------------
extern "C" void kernel_launch(void* const* d_in, const int* in_sizes, int n_in,
                              void* d_out, int out_size, void* d_ws, size_t ws_size,
                              hipStream_t stream) {
  const float* src  = (const float*)d_in[0];
  const float* relf = (const float*)d_in[1];
  const float* rel_w = (const float*)d_in[2];
  const float* rel_b = (const float*)d_in[3];
  const float* w1 = (const float*)d_in[4];
  const float* b1 = (const float*)d_in[5];
  const float* w2 = (const float*)d_in[6];
  const float* b2 = (const float*)d_in[7];
  const float* g1  = (const float*)d_in[8];
  const float* be1 = (const float*)d_in[9];
  const float* g2  = (const float*)d_in[10];
  const float* be2 = (const float*)d_in[11];
  float* out = (float*)d_out;

  float* ws = (float*)d_ws;
  ushort_t* qwb  = (ushort_t*)(ws);                 // 524288 bf16
  float*    qb   = ws + 262144;                     // 8192 f
  ushort_t* srcb = (ushort_t*)(ws + 270336);        // 524288 bf16
  ushort_t* Sb   = (ushort_t*)(ws + 532480);        // 4194304 bf16
  float*    attn = ws + 2629632;                    // 524288 f
  float*    x    = ws + 3153920;                    // 524288 f
  ushort_t* xb   = (ushort_t*)(ws + 3678208);       // 524288 bf16
  ushort_t* w1b  = (ushort_t*)(ws + 3940352);       // 1048576 bf16
  ushort_t* w2b  = (ushort_t*)(ws + 4464640);       // 1048576 bf16
  ushort_t* ffb  = (ushort_t*)(ws + 4988928);       // 2097152 bf16
  float*    p    = ws + 6037504;                    // 2097152 f

  qw_conv_kernel   <<<1088, 256, 0, stream>>>(src, rel_w, rel_b, w1, w2,
                                              qwb, qb, srcb, w1b, w2b);
  rel_stream_kernel<<<1024, 256, 0, stream>>>(relf, qwb, qb, Sb);
  softmax_pv_kernel<<<dim3(16, 32), 256, 0, stream>>>(Sb, srcb, src, attn);
  ln1_kernel       <<<1024, 256, 0, stream>>>(src, attn, g1, be1, x, xb);
  gemm_ffn1        <<<dim3(16, 32), 256, 0, stream>>>(xb, w1b, b1, ffb);
  gemm_ffn2        <<<dim3(16, 8, 4), 256, 0, stream>>>(ffb, w2b, p);
  ln2_kernel       <<<1024, 256, 0, stream>>>(p, x, b2, g2, be2, out);
}

// Round 7
// 84.463 us; speedup vs baseline: 4.1925x; 1.1394x over previous
//
#include <hip/hip_runtime.h>
#include <math.h>

#define LN_EPS 1e-5f
// B=2 L=512 D=512 H=8 DH=64 C=64 F=2048
// Sb layout (bf16): Sb[b,i,h,j] = Sb[((b*512+i)*8 + h)*512 + j]

typedef __bf16 bf16x8 __attribute__((ext_vector_type(8)));
typedef unsigned short u16x8 __attribute__((ext_vector_type(8)));
typedef float f32x4 __attribute__((ext_vector_type(4)));
typedef unsigned short ushort_t;
typedef unsigned int uint_t;

__device__ inline ushort_t f2bf(float f) {
  uint_t u = __float_as_uint(f);
  return (ushort_t)((u + 0x7FFFu + ((u >> 16) & 1u)) >> 16);
}
__device__ inline float bf2f(ushort_t b) {
  return __uint_as_float(((uint_t)b) << 16);
}
// v_cvt_pk_bf16_f32: D[15:0]=bf16(S0), D[31:16]=bf16(S1)
__device__ inline uint_t cvtpk(float lo, float hi) {
  uint_t r;
  asm("v_cvt_pk_bf16_f32 %0, %1, %2" : "=v"(r) : "v"(lo), "v"(hi));
  return r;
}
__device__ inline bf16x8 cvt8pk(float4 a, float4 b) {
  uint4 v;
  v.x = cvtpk(a.x, a.y); v.y = cvtpk(a.z, a.w);
  v.z = cvtpk(b.x, b.y); v.w = cvtpk(b.z, b.w);
  return __builtin_bit_cast(bf16x8, v);
}

// ---------------------------------------------------------------------------
// K1 "qw_conv": blocks 0..1023: qwb[b,i,h,c] (bf16) + qb[b,i,h].
// blocks 1024..1087: convert src->srcb, w1->w1b, w2->w2b.
// ---------------------------------------------------------------------------
__global__ __launch_bounds__(256) void qw_conv_kernel(
    const float* __restrict__ src, const float* __restrict__ rel_w,
    const float* __restrict__ rel_b,
    const float* __restrict__ w1, const float* __restrict__ w2,
    ushort_t* __restrict__ qwb, float* __restrict__ qb,
    ushort_t* __restrict__ srcb, ushort_t* __restrict__ w1b,
    ushort_t* __restrict__ w2b)
{
  const int tid = threadIdx.x;
  if (blockIdx.x >= 1024) {
    const int cb = blockIdx.x - 1024;          // 0..63
    const int tg = cb*256 + tid;               // 0..16383
    for (int it = tg; it < 65536; it += 16384) {
      const int i = it*8;
      const float4 a = *(const float4*)(src + i);
      const float4 b = *(const float4*)(src + i + 4);
      uint4 v;
      v.x = cvtpk(a.x, a.y); v.y = cvtpk(a.z, a.w);
      v.z = cvtpk(b.x, b.y); v.w = cvtpk(b.z, b.w);
      *(uint4*)(srcb + i) = v;
    }
    for (int it = tg; it < 131072; it += 16384) {
      const int i = it*8;
      const float4 a = *(const float4*)(w1 + i);
      const float4 b = *(const float4*)(w1 + i + 4);
      uint4 v;
      v.x = cvtpk(a.x, a.y); v.y = cvtpk(a.z, a.w);
      v.z = cvtpk(b.x, b.y); v.w = cvtpk(b.z, b.w);
      *(uint4*)(w1b + i) = v;
    }
    for (int it = tg; it < 131072; it += 16384) {
      const int i = it*8;
      const float4 a = *(const float4*)(w2 + i);
      const float4 b = *(const float4*)(w2 + i + 4);
      uint4 v;
      v.x = cvtpk(a.x, a.y); v.y = cvtpk(a.z, a.w);
      v.z = cvtpk(b.x, b.y); v.w = cvtpk(b.z, b.w);
      *(uint4*)(w2b + i) = v;
    }
    return;
  }

  const int bi = blockIdx.x;     // b*512 + i
  __shared__ float q_sh[512];
  q_sh[tid]       = src[bi*512 + tid];
  q_sh[tid + 256] = src[bi*512 + tid + 256];
  __syncthreads();
  for (int idx = tid; idx < 512; idx += 256) {
    const int h = idx >> 6, c = idx & 63;
    float s = 0.f;
    #pragma unroll 8
    for (int d = 0; d < 64; ++d)
      s = fmaf(q_sh[h*64+d], rel_w[(h*64+d)*64 + c], s);
    qwb[(size_t)bi*512 + idx] = f2bf(s);
  }
  if (tid < 8) {
    float s = 0.f;
    for (int d = 0; d < 64; ++d) s = fmaf(q_sh[tid*64+d], rel_b[tid*64+d], s);
    qb[bi*8 + tid] = s;
  }
}

// ---------------------------------------------------------------------------
// K2 "rel_stream": pure 134MB stream, 8 waves/block:
//   Sb[b,i,h,j] = bf16( sum_c RF[b,i,j,c]*qw[h,c] + qb[h] ) via MFMA.
// ---------------------------------------------------------------------------
__global__ __launch_bounds__(512) void rel_stream_kernel(
    const float* __restrict__ relf, const ushort_t* __restrict__ qwb,
    const float* __restrict__ qb, ushort_t* __restrict__ Sb)
{
  const int bi = blockIdx.x;           // b*512 + i
  const int tid = threadIdx.x;
  const int lane = tid & 63, w = tid >> 6;   // w 0..7
  const int hl = lane & 15;          // D col (head), valid < 8
  const int kc = lane >> 4;          // k-chunk 0..3
  const int h  = hl & 7;

  const bf16x8 b0 = *(const bf16x8*)&qwb[(size_t)bi*512 + h*64 + kc*8];
  const bf16x8 b1 = *(const bf16x8*)&qwb[(size_t)bi*512 + h*64 + 32 + kc*8];
  const float qbv = qb[bi*8 + h];
  ushort_t* Sp = Sb + ((size_t)bi*8 + h)*512;

  #pragma unroll
  for (int t = 0; t < 4; ++t) {
    const int j0 = (t*8 + w)*16;             // 32 j-tiles over 8 waves x 4 iters
    const int j  = j0 + hl;                  // A row
    const float* rf = relf + ((size_t)bi*512 + j)*64 + kc*8;
    const float4 x0 = *(const float4*)rf;
    const float4 x1 = *(const float4*)(rf + 4);
    const float4 y0 = *(const float4*)(rf + 32);
    const float4 y1 = *(const float4*)(rf + 36);
    const bf16x8 a0 = cvt8pk(x0, x1);
    const bf16x8 a1 = cvt8pk(y0, y1);
    f32x4 acc = {0.f, 0.f, 0.f, 0.f};
    acc = __builtin_amdgcn_mfma_f32_16x16x32_bf16(a0, b0, acc, 0, 0, 0);
    acc = __builtin_amdgcn_mfma_f32_16x16x32_bf16(a1, b1, acc, 0, 0, 0);
    if (hl < 8) {
      uint2 pk;
      pk.x = cvtpk(acc[0] + qbv, acc[1] + qbv);
      pk.y = cvtpk(acc[2] + qbv, acc[3] + qbv);
      *(uint2*)&Sp[j0 + kc*4] = pk;
    }
  }
}

// ---------------------------------------------------------------------------
// K3: per (bh, it=16 rows), 8 waves: base scores (MFMA) -> LDS;
//     softmax( 0.125*base + Sb ) -> Pt; PV (bf16 V, fp32 acc) -> attn_out
// ---------------------------------------------------------------------------
__global__ __launch_bounds__(512) void softmax_pv_kernel(
    const ushort_t* __restrict__ Sb, const ushort_t* __restrict__ srcb,
    float* __restrict__ attn_out)
{
  const int bh = blockIdx.x, it = blockIdx.y;
  const int b = bh >> 3, h = bh & 7;
  const int i0 = it * 16;
  const int tid = threadIdx.x;
  const int lane = tid & 63, w = tid >> 6;   // w 0..7
  __shared__ float Ssm[16][516];
  __shared__ float Pt[512*20];

  // ---- Phase A: base scores Q.K^T via MFMA ----
  {
    const int il = lane & 15, kc = lane >> 4;
    const bf16x8 aq0 = *(const bf16x8*)&srcb[(size_t)(b*512 + i0 + il)*512 + h*64 + kc*8];
    const bf16x8 aq1 = *(const bf16x8*)&srcb[(size_t)(b*512 + i0 + il)*512 + h*64 + 32 + kc*8];
    #pragma unroll
    for (int t = 0; t < 4; ++t) {
      const int jt = t*8 + w;                // 0..31
      const int j  = jt*16 + il;             // B col
      const bf16x8 bk0 = *(const bf16x8*)&srcb[(size_t)(b*512 + j)*512 + h*64 + kc*8];
      const bf16x8 bk1 = *(const bf16x8*)&srcb[(size_t)(b*512 + j)*512 + h*64 + 32 + kc*8];
      f32x4 acc = {0.f, 0.f, 0.f, 0.f};
      acc = __builtin_amdgcn_mfma_f32_16x16x32_bf16(aq0, bk0, acc, 0, 0, 0);
      acc = __builtin_amdgcn_mfma_f32_16x16x32_bf16(aq1, bk1, acc, 0, 0, 0);
      #pragma unroll
      for (int r = 0; r < 4; ++r) Ssm[kc*4 + r][jt*16 + il] = acc[r];
    }
  }
  __syncthreads();

  // ---- Phase B: softmax rows (2 rows per wave) ----
  #pragma unroll
  for (int k = 0; k < 2; ++k) {
    const int row = w*2 + k;
    const ushort_t* Srow = Sb + ((size_t)(b*512 + i0 + row)*8 + h)*512;
    float v[8];
    float m = -1e30f;
    #pragma unroll
    for (int r = 0; r < 8; ++r) {
      v[r] = Ssm[row][lane + 64*r]*0.125f + bf2f(Srow[lane + 64*r]);
      m = fmaxf(m, v[r]);
    }
    #pragma unroll
    for (int o = 32; o > 0; o >>= 1) m = fmaxf(m, __shfl_xor(m, o, 64));
    float s = 0.f;
    #pragma unroll
    for (int r = 0; r < 8; ++r) { v[r] = __expf(v[r] - m); s += v[r]; }
    #pragma unroll
    for (int o = 32; o > 0; o >>= 1) s += __shfl_xor(s, o, 64);
    const float inv = 1.f / s;
    #pragma unroll
    for (int r = 0; r < 8; ++r) Pt[(lane + 64*r)*20 + row] = v[r] * inv;
  }
  __syncthreads();

  // ---- Phase C: PV (bf16 V, fp32 acc), 2 i-rows per thread ----
  {
    const int d = lane, ig = w;
    const ushort_t* V = srcb + (size_t)(b*512)*512 + h*64 + d;
    float acc0=0.f, acc1=0.f;
    #pragma unroll 8
    for (int j = 0; j < 512; ++j) {
      const float vv = bf2f(V[(size_t)j*512]);
      const float2 p = *(const float2*)&Pt[j*20 + ig*2];
      acc0 = fmaf(p.x, vv, acc0); acc1 = fmaf(p.y, vv, acc1);
    }
    float* out = attn_out + ((size_t)(b*512) + i0)*512 + h*64 + d;
    out[(size_t)(ig*2+0)*512] = acc0;
    out[(size_t)(ig*2+1)*512] = acc1;
  }
}

// ---------------------------------------------------------------------------
// K4: x = LN(src + attn_out) * g1 + be1 ; also emit x in bf16
// ---------------------------------------------------------------------------
__global__ __launch_bounds__(256) void ln1_kernel(
    const float* __restrict__ a, const float* __restrict__ bb,
    const float* __restrict__ g, const float* __restrict__ be,
    float* __restrict__ out, ushort_t* __restrict__ xb)
{
  const int bi = blockIdx.x, tid = threadIdx.x;
  const int d0 = tid * 2;
  const float2 xa = *(const float2*)&a [bi*512 + d0];
  const float2 xv = *(const float2*)&bb[bi*512 + d0];
  const float y0 = xa.x + xv.x;
  const float y1 = xa.y + xv.y;
  float s1 = y0 + y1, s2 = y0*y0 + y1*y1;
  #pragma unroll
  for (int o = 32; o > 0; o >>= 1) { s1 += __shfl_xor(s1, o, 64); s2 += __shfl_xor(s2, o, 64); }
  __shared__ float r1[4], r2[4];
  const int w = tid >> 6;
  if ((tid & 63) == 0) { r1[w] = s1; r2[w] = s2; }
  __syncthreads();
  const float t1 = r1[0] + r1[1] + r1[2] + r1[3];
  const float t2 = r2[0] + r2[1] + r2[2] + r2[3];
  const float mu  = t1 * (1.f/512.f);
  const float var = t2 * (1.f/512.f) - mu*mu;
  const float rs  = rsqrtf(var + LN_EPS);
  const float2 gg = *(const float2*)&g [d0];
  const float2 bv = *(const float2*)&be[d0];
  const float o0 = (y0 - mu)*rs*gg.x + bv.x;
  const float o1 = (y1 - mu)*rs*gg.y + bv.y;
  out[bi*512 + d0]     = o0;
  out[bi*512 + d0 + 1] = o1;
  *(uint_t*)&xb[bi*512 + d0] = cvtpk(o0, o1);
}

// ---------------------------------------------------------------------------
// K5: MFMA GEMM  ff = leaky_relu(xb @ w1b^T + b1), bf16 out
// BM=64 BN=64 BK=64; 4 waves 2x2, wave tile 32x32 (2x2 frags); grid (16,32)
// ---------------------------------------------------------------------------
__global__ __launch_bounds__(256) void gemm_ffn1(
    const ushort_t* __restrict__ A,   // [1024][512]
    const ushort_t* __restrict__ B,   // [2048][512]
    const float* __restrict__ bias, ushort_t* __restrict__ C)  // [1024][2048]
{
  __shared__ ushort_t Asm[64*64];
  __shared__ ushort_t Bsm[64*64];
  const int tid = threadIdx.x;
  const int m0 = blockIdx.x * 64, n0 = blockIdx.y * 64;
  const int lane = tid & 63;
  const int wr = (tid >> 7) & 1, wc = (tid >> 6) & 1;

  const int row = tid >> 2, r7 = row & 7;
  const int cb  = (tid & 3) * 2;

  f32x4 acc[2][2] = {};
  for (int kt = 0; kt < 8; ++kt) {
    const uint4* ga = (const uint4*)(A + (size_t)(m0 + row)*512 + kt*64);
    const uint4 av0 = ga[cb], av1 = ga[cb+1];
    const uint4* gb = (const uint4*)(B + (size_t)(n0 + row)*512 + kt*64);
    const uint4 bv0 = gb[cb], bv1 = gb[cb+1];
    __syncthreads();
    *(uint4*)&Asm[row*64 + (((cb+0) ^ r7) << 3)] = av0;
    *(uint4*)&Asm[row*64 + (((cb+1) ^ r7) << 3)] = av1;
    *(uint4*)&Bsm[row*64 + (((cb+0) ^ r7) << 3)] = bv0;
    *(uint4*)&Bsm[row*64 + (((cb+1) ^ r7) << 3)] = bv1;
    __syncthreads();
    #pragma unroll
    for (int kk = 0; kk < 2; ++kk) {
      bf16x8 af[2], bfm[2];
      #pragma unroll
      for (int fm = 0; fm < 2; ++fm) {
        const int r = wr*32 + fm*16 + (lane & 15);
        const int c = (kk*4 + (lane >> 4)) ^ (r & 7);
        af[fm] = *(const bf16x8*)&Asm[r*64 + c*8];
      }
      #pragma unroll
      for (int fn = 0; fn < 2; ++fn) {
        const int r = wc*32 + fn*16 + (lane & 15);
        const int c = (kk*4 + (lane >> 4)) ^ (r & 7);
        bfm[fn] = *(const bf16x8*)&Bsm[r*64 + c*8];
      }
      #pragma unroll
      for (int fm = 0; fm < 2; ++fm)
        #pragma unroll
        for (int fn = 0; fn < 2; ++fn)
          acc[fm][fn] = __builtin_amdgcn_mfma_f32_16x16x32_bf16(af[fm], bfm[fn], acc[fm][fn], 0, 0, 0);
    }
  }
  #pragma unroll
  for (int fn = 0; fn < 2; ++fn) {
    const int col = n0 + wc*32 + fn*16 + (lane & 15);
    const float bb = bias[col];
    #pragma unroll
    for (int fm = 0; fm < 2; ++fm) {
      #pragma unroll
      for (int r = 0; r < 4; ++r) {
        const int orow = m0 + wr*32 + fm*16 + (lane >> 4)*4 + r;
        float t = acc[fm][fn][r] + bb;
        t = t > 0.f ? t : 0.01f*t;
        C[(size_t)orow*2048 + col] = f2bf(t);
      }
    }
  }
}

// ---------------------------------------------------------------------------
// K6: MFMA GEMM  p[z] = ff @ w2b^T over K-slice z*512..+512, fp32 partials
// BM=64 BN=64; grid (16, 8, 4)
// ---------------------------------------------------------------------------
__global__ __launch_bounds__(256) void gemm_ffn2(
    const ushort_t* __restrict__ A,   // ff [1024][2048]
    const ushort_t* __restrict__ B,   // w2b [512][2048]
    float* __restrict__ P)            // [4][1024][512]
{
  __shared__ ushort_t Asm[64*64];
  __shared__ ushort_t Bsm[64*64];
  const int tid = threadIdx.x;
  const int m0 = blockIdx.x * 64, n0 = blockIdx.y * 64;
  const int kbase = blockIdx.z * 512;
  float* outp = P + (size_t)blockIdx.z * 524288;
  const int lane = tid & 63;
  const int wr = (tid >> 7) & 1, wc = (tid >> 6) & 1;

  const int row = tid >> 2, r7 = row & 7;
  const int cb  = (tid & 3) * 2;

  f32x4 acc[2][2] = {};
  for (int kt = 0; kt < 8; ++kt) {
    const uint4* ga = (const uint4*)(A + (size_t)(m0 + row)*2048 + kbase + kt*64);
    const uint4 av0 = ga[cb], av1 = ga[cb+1];
    const uint4* gb = (const uint4*)(B + (size_t)(n0 + row)*2048 + kbase + kt*64);
    const uint4 bv0 = gb[cb], bv1 = gb[cb+1];
    __syncthreads();
    *(uint4*)&Asm[row*64 + (((cb+0) ^ r7) << 3)] = av0;
    *(uint4*)&Asm[row*64 + (((cb+1) ^ r7) << 3)] = av1;
    *(uint4*)&Bsm[row*64 + (((cb+0) ^ r7) << 3)] = bv0;
    *(uint4*)&Bsm[row*64 + (((cb+1) ^ r7) << 3)] = bv1;
    __syncthreads();
    #pragma unroll
    for (int kk = 0; kk < 2; ++kk) {
      bf16x8 af[2], bfm[2];
      #pragma unroll
      for (int fm = 0; fm < 2; ++fm) {
        const int r = wr*32 + fm*16 + (lane & 15);
        const int c = (kk*4 + (lane >> 4)) ^ (r & 7);
        af[fm] = *(const bf16x8*)&Asm[r*64 + c*8];
      }
      #pragma unroll
      for (int fn = 0; fn < 2; ++fn) {
        const int r = wc*32 + fn*16 + (lane & 15);
        const int c = (kk*4 + (lane >> 4)) ^ (r & 7);
        bfm[fn] = *(const bf16x8*)&Bsm[r*64 + c*8];
      }
      #pragma unroll
      for (int fm = 0; fm < 2; ++fm)
        #pragma unroll
        for (int fn = 0; fn < 2; ++fn)
          acc[fm][fn] = __builtin_amdgcn_mfma_f32_16x16x32_bf16(af[fm], bfm[fn], acc[fm][fn], 0, 0, 0);
    }
  }
  #pragma unroll
  for (int fn = 0; fn < 2; ++fn) {
    const int col = n0 + wc*32 + fn*16 + (lane & 15);
    #pragma unroll
    for (int fm = 0; fm < 2; ++fm) {
      #pragma unroll
      for (int r = 0; r < 4; ++r) {
        const int orow = m0 + wr*32 + fm*16 + (lane >> 4)*4 + r;
        outp[(size_t)orow*512 + col] = acc[fm][fn][r];
      }
    }
  }
}

// ---------------------------------------------------------------------------
// K7: out = LN(x + p0+p1+p2+p3 + b2) * g2 + be2
// ---------------------------------------------------------------------------
__global__ __launch_bounds__(256) void ln2_kernel(
    const float* __restrict__ p, const float* __restrict__ x,
    const float* __restrict__ b2, const float* __restrict__ g2,
    const float* __restrict__ be2, float* __restrict__ out)
{
  const int bi = blockIdx.x, tid = threadIdx.x;
  const int d0 = tid * 2;
  const float2 a0 = *(const float2*)&p[bi*512 + d0];
  const float2 a1 = *(const float2*)&p[524288 + bi*512 + d0];
  const float2 a2 = *(const float2*)&p[1048576 + bi*512 + d0];
  const float2 a3 = *(const float2*)&p[1572864 + bi*512 + d0];
  const float2 xr = *(const float2*)&x [bi*512 + d0];
  const float2 bb = *(const float2*)&b2[d0];
  const float y0 = a0.x + a1.x + a2.x + a3.x + bb.x + xr.x;
  const float y1 = a0.y + a1.y + a2.y + a3.y + bb.y + xr.y;
  float s1 = y0 + y1, s2 = y0*y0 + y1*y1;
  #pragma unroll
  for (int o = 32; o > 0; o >>= 1) { s1 += __shfl_xor(s1, o, 64); s2 += __shfl_xor(s2, o, 64); }
  __shared__ float r1[4], r2[4];
  const int w = tid >> 6;
  if ((tid & 63) == 0) { r1[w] = s1; r2[w] = s2; }
  __syncthreads();
  const float t1 = r1[0] + r1[1] + r1[2] + r1[3];
  const float t2 = r2[0] + r2[1] + r2[2] + r2[3];
  const float mu  = t1 * (1.f/512.f);
  const float var = t2 * (1.f/512.f) - mu*mu;
  const float rs  = rsqrtf(var + LN_EPS);
  const float2 g  = *(const float2*)&g2 [d0];
  const float2 be = *(const float2*)&be2[d0];
  out[bi*512 + d0]     = (y0 - mu)*rs*g.x + be.x;
  out[bi*512 + d0 + 1] = (y1 - mu)*rs*g.y + be.y;
}

// ---------------------------------------------------------------------------
extern "C" void kernel_launch(void* const* d_in, const int* in_sizes, int n_in,
                              void* d_out, int out_size, void* d_ws, size_t ws_size,
                              hipStream_t stream) {
  const float* src  = (const float*)d_in[0];
  const float* relf = (const float*)d_in[1];
  const float* rel_w = (const float*)d_in[2];
  const float* rel_b = (const float*)d_in[3];
  const float* w1 = (const float*)d_in[4];
  const float* b1 = (const float*)d_in[5];
  const float* w2 = (const float*)d_in[6];
  const float* b2 = (const float*)d_in[7];
  const float* g1  = (const float*)d_in[8];
  const float* be1 = (const float*)d_in[9];
  const float* g2  = (const float*)d_in[10];
  const float* be2 = (const float*)d_in[11];
  float* out = (float*)d_out;

  float* ws = (float*)d_ws;
  ushort_t* qwb  = (ushort_t*)(ws);                 // 524288 bf16
  float*    qb   = ws + 262144;                     // 8192 f
  ushort_t* srcb = (ushort_t*)(ws + 270336);        // 524288 bf16
  ushort_t* Sb   = (ushort_t*)(ws + 532480);        // 4194304 bf16
  float*    attn = ws + 2629632;                    // 524288 f
  float*    x    = ws + 3153920;                    // 524288 f
  ushort_t* xb   = (ushort_t*)(ws + 3678208);       // 524288 bf16
  ushort_t* w1b  = (ushort_t*)(ws + 3940352);       // 1048576 bf16
  ushort_t* w2b  = (ushort_t*)(ws + 4464640);       // 1048576 bf16
  ushort_t* ffb  = (ushort_t*)(ws + 4988928);       // 2097152 bf16
  float*    p    = ws + 6037504;                    // 2097152 f

  qw_conv_kernel   <<<1088, 256, 0, stream>>>(src, rel_w, rel_b, w1, w2,
                                              qwb, qb, srcb, w1b, w2b);
  rel_stream_kernel<<<1024, 512, 0, stream>>>(relf, qwb, qb, Sb);
  softmax_pv_kernel<<<dim3(16, 32), 512, 0, stream>>>(Sb, srcb, attn);
  ln1_kernel       <<<1024, 256, 0, stream>>>(src, attn, g1, be1, x, xb);
  gemm_ffn1        <<<dim3(16, 32), 256, 0, stream>>>(xb, w1b, b1, ffb);
  gemm_ffn2        <<<dim3(16, 8, 4), 256, 0, stream>>>(ffb, w2b, p);
  ln2_kernel       <<<1024, 256, 0, stream>>>(p, x, b2, g2, be2, out);
}